// Round 7
// baseline (385.190 us; speedup 1.0000x reference)
//
#include <hip/hip_runtime.h>
#include <stdint.h>

#define NH 12
#define DMODEL 768
#define HDK 64
#define SEQ 4096
#define NB 2

typedef __attribute__((ext_vector_type(8))) short bf16x8;
typedef __attribute__((ext_vector_type(4))) short s16x4;
typedef __attribute__((ext_vector_type(4))) float f32x4;
typedef __attribute__((ext_vector_type(16))) float f32x16;

#define LOG2E 1.44269504f
#define QSCALE 0.18033688f   /* 0.125 * log2(e), folded into Q at projection */
/* No fixed softmax shift: p = exp2(score*log2e) <= 2^4 = 16 (|s*log2e|<4);
   any consistent scale cancels exactly in O/l. Masked-out cols get
   adds = -14427 -> exp2 flushes to exact 0. */

__device__ __forceinline__ unsigned short f2bf(float x) {
    union { float f; unsigned u; } v; v.f = x;
    unsigned r = v.u + 0x7FFFu + ((v.u >> 16) & 1u);
    return (unsigned short)(r >> 16);
}

// pack two fp32 -> two bf16, round-half-up (2 add + 1 perm)
__device__ __forceinline__ unsigned pack2bf(float a, float b) {
    union { float f; unsigned u; } x, y; x.f = a; y.f = b;
    return __builtin_amdgcn_perm(y.u + 0x8000u, x.u + 0x8000u, 0x07060302u);
}

// pack two fp32 -> two bf16, TRUNCATING (1 perm); P only (bias cancels in ratio)
__device__ __forceinline__ unsigned pack2bf_t(float a, float b) {
    union { float f; unsigned u; } x, y; x.f = a; y.f = b;
    return __builtin_amdgcn_perm(y.u, x.u, 0x07060302u);
}

// async global -> LDS: dest = wave-uniform base + lane*16
__device__ __forceinline__ void lds_dma16(const void* g, void* l) {
    __builtin_amdgcn_global_load_lds(
        (const __attribute__((address_space(1))) void*)g,
        (__attribute__((address_space(3))) void*)l, 16, 0, 0);
}

// ---------------------------------------------------------------------------
// Kernel 1: W [k][n] fp32 -> Wt [n][k] bf16
// ---------------------------------------------------------------------------
__global__ __launch_bounds__(256) void wt_kernel(
    const float* __restrict__ Wq, const float* __restrict__ Wk,
    const float* __restrict__ Wv, unsigned short* __restrict__ Wt) {
    __shared__ float ts[32][33];
    int mat = blockIdx.z;
    const float* W = (mat == 0) ? Wq : ((mat == 1) ? Wk : Wv);
    unsigned short* out = Wt + (size_t)mat * DMODEL * DMODEL;
    int k0 = blockIdx.x * 32;
    int n0 = blockIdx.y * 32;
    int t = threadIdx.x;
    int row = t >> 3, c4 = (t & 7) * 4;
    float4 v = *(const float4*)&W[(size_t)(k0 + row) * DMODEL + n0 + c4];
    ts[row][c4 + 0] = v.x; ts[row][c4 + 1] = v.y;
    ts[row][c4 + 2] = v.z; ts[row][c4 + 3] = v.w;
    __syncthreads();
    s16x4 o;
    o[0] = (short)f2bf(ts[c4 + 0][row]);
    o[1] = (short)f2bf(ts[c4 + 1][row]);
    o[2] = (short)f2bf(ts[c4 + 2][row]);
    o[3] = (short)f2bf(ts[c4 + 3][row]);
    *(s16x4*)&out[(size_t)(n0 + row) * DMODEL + k0 + c4] = o;
}

// ---------------------------------------------------------------------------
// Kernel 1b: A fp32 [3][8192][768] -> bf16, one-shot (BW-bound pre-pass).
// ---------------------------------------------------------------------------
__global__ __launch_bounds__(256) void abf_kernel(
    const float* __restrict__ Aq, const float* __restrict__ Ak,
    const float* __restrict__ Av, unsigned short* __restrict__ Abf) {
    int mat = blockIdx.y;
    const float* A = (mat == 0) ? Aq : ((mat == 1) ? Ak : Av);
    unsigned short* o = Abf + (size_t)mat * NB * SEQ * DMODEL;
    int t = blockIdx.x * 256 + threadIdx.x;
    #pragma unroll
    for (int i = 0; i < 4; ++i) {
        size_t e = ((size_t)i * 196608 + t) * 8;   // 768*256*32 = 6291456 elems
        float4 lo = *(const float4*)&A[e];
        float4 hi = *(const float4*)&A[e + 4];
        uint4 r;
        r.x = pack2bf(lo.x, lo.y); r.y = pack2bf(lo.z, lo.w);
        r.z = pack2bf(hi.x, hi.y); r.w = pack2bf(hi.z, hi.w);
        *(uint4*)&o[e] = r;
    }
}

// ---------------------------------------------------------------------------
// Kernel 2 (primary): QKV GEMM v8 — FROZEN from round 6 (best measured total).
// Single-barrier 2-phase K-loop + LDS-transposed coalesced epilogue.
// ---------------------------------------------------------------------------
__global__ __launch_bounds__(256, 3) void qkv_gemm8(
    const unsigned short* __restrict__ Abf, const unsigned short* __restrict__ Wt,
    const float* __restrict__ bq, const float* __restrict__ bk,
    const float* __restrict__ bv,
    unsigned short* __restrict__ Qw, unsigned short* __restrict__ Kw,
    unsigned short* __restrict__ Vt) {
    __shared__ __align__(16) char smem[32768];
    unsigned short* AsB = (unsigned short*)smem;            // [2][4096] shorts
    unsigned short* BsB = (unsigned short*)(smem + 16384);  // [2][4096] shorts
    unsigned short* T   = (unsigned short*)smem;            // epilogue [128][128]

    int lin = blockIdx.x;
    int swz = (lin & 7) * 144 + (lin >> 3);   // XCD-chunked (1152 % 8 == 0)
    int mat = swz / 384;
    int rr = swz - mat * 384;
    int mblk = rr / 6;
    int nblk = rr - mblk * 6;                 // n fastest: A-panel sharers adjacent
    const unsigned short* A = Abf + (size_t)mat * NB * SEQ * DMODEL;
    const unsigned short* W = Wt + (size_t)mat * DMODEL * DMODEL;
    const float* bias = (mat == 0) ? bq : ((mat == 1) ? bk : bv);
    int m0 = mblk * 128;
    int n0 = nblk * 128;
    int tid = threadIdx.x;
    int lane = tid & 63, wv = tid >> 6;
    int wm = (wv & 1) * 64, wn = (wv >> 1) * 64;
    int lm = lane & 15, quad = lane >> 4;

    const unsigned short* aS[2];
    const unsigned short* bS[2];
    #pragma unroll
    for (int i = 0; i < 2; ++i) {
        int g = i * 256 + tid;
        int R = g >> 2, c = g & 3, ch = c ^ (R & 3);
        aS[i] = A + (size_t)(m0 + R) * DMODEL + ch * 8;
        bS[i] = W + (size_t)(n0 + R) * DMODEL + ch * 8;
    }

    f32x4 acc[4][4] = {};
    const int sx3 = lm & 3;
    const bool swapC = (mat < 2);

    #pragma unroll
    for (int i = 0; i < 2; ++i) {
        lds_dma16(aS[i], AsB + (i * 256 + wv * 64) * 8);
        lds_dma16(bS[i], BsB + (i * 256 + wv * 64) * 8);
        aS[i] += 32; bS[i] += 32;
    }
    __syncthreads();

    for (int kt = 0; kt < 24; ++kt) {
        int cur = kt & 1;
        if (kt < 23) {
            unsigned short* ad = AsB + (cur ^ 1) * 4096;
            unsigned short* bd = BsB + (cur ^ 1) * 4096;
            #pragma unroll
            for (int i = 0; i < 2; ++i) {
                lds_dma16(aS[i], ad + (i * 256 + wv * 64) * 8);
                lds_dma16(bS[i], bd + (i * 256 + wv * 64) * 8);
                aS[i] += 32; bS[i] += 32;
            }
        }
        const unsigned short* Ac = AsB + cur * 4096;
        const unsigned short* Bc = BsB + cur * 4096;
        bf16x8 af[4], bfr[4];
        #pragma unroll
        for (int i = 0; i < 4; ++i)
            af[i] = *(const bf16x8*)&Ac[(wm + i * 16 + lm) * 32 +
                                        ((quad ^ sx3) << 3)];
        #pragma unroll
        for (int j = 0; j < 4; ++j)
            bfr[j] = *(const bf16x8*)&Bc[(wn + j * 16 + lm) * 32 +
                                         ((quad ^ sx3) << 3)];
        if (swapC) {
            #pragma unroll
            for (int i = 0; i < 4; ++i)
                #pragma unroll
                for (int j = 0; j < 4; ++j)
                    acc[i][j] = __builtin_amdgcn_mfma_f32_16x16x32_bf16(
                        bfr[j], af[i], acc[i][j], 0, 0, 0);
        } else {
            #pragma unroll
            for (int i = 0; i < 4; ++i)
                #pragma unroll
                for (int j = 0; j < 4; ++j)
                    acc[i][j] = __builtin_amdgcn_mfma_f32_16x16x32_bf16(
                        af[i], bfr[j], acc[i][j], 0, 0, 0);
        }
        __syncthreads();   // drains this kt's reads + the prefetch DMAs
    }

    // ---- epilogue phase 1: bias+scale+pack into LDS tile (swizzled) ----
    if (swapC) {
        float sc = (mat == 0) ? QSCALE : 1.0f;
        #pragma unroll
        for (int j = 0; j < 4; ++j) {
            int nb = wn + j * 16 + quad * 4;
            f32x4 bvv = *(const f32x4*)&bias[n0 + nb];
            #pragma unroll
            for (int i = 0; i < 4; ++i) {
                int s = wm + i * 16 + lm;
                s16x4 o;
                #pragma unroll
                for (int r = 0; r < 4; ++r)
                    o[r] = (short)f2bf((acc[i][j][r] + bvv[r]) * sc);
                int idx = s * 128 + ((((nb >> 3) ^ (s & 15)) << 3) | (nb & 7));
                *(s16x4*)&T[idx] = o;
            }
        }
    } else {
        #pragma unroll
        for (int j = 0; j < 4; ++j) {
            int n = wn + j * 16 + lm;
            float bvv = bias[n0 + n];
            #pragma unroll
            for (int i = 0; i < 4; ++i) {
                int mg = wm + i * 16 + quad * 4;
                s16x4 o;
                #pragma unroll
                for (int r = 0; r < 4; ++r) o[r] = (short)f2bf(acc[i][j][r] + bvv);
                int idx = n * 128 + ((((mg >> 3) ^ (n & 15)) << 3) | (mg & 7));
                *(s16x4*)&T[idx] = o;
            }
        }
    }
    __syncthreads();

    // ---- epilogue phase 2: coalesced readout (8 x 16B per thread) ----
    int row8 = tid >> 4, chunk = tid & 15;
    if (swapC) {
        unsigned short* outp = (mat == 0) ? Qw : Kw;
        int n = chunk * 8;
        int h = (n0 + n) >> 6, dk = (n0 + n) & 63;
        #pragma unroll
        for (int it = 0; it < 8; ++it) {
            int rrow = it * 16 + row8;
            int s = m0 + rrow;
            int b = s >> 12, ss = s & 4095;
            uint4 v = *(const uint4*)&T[rrow * 128 +
                                        ((chunk ^ (rrow & 15)) << 3)];
            *(uint4*)&outp[((size_t)(b * NH + h) * SEQ + ss) * HDK + dk] = v;
        }
    } else {
        int s = m0 + chunk * 8;
        int b = s >> 12, ss = s & 4095;
        #pragma unroll
        for (int it = 0; it < 8; ++it) {
            int rrow = it * 16 + row8;
            int dk = (n0 + rrow) & 63, h = (n0 + rrow) >> 6;
            uint4 v = *(const uint4*)&T[rrow * 128 +
                                        ((chunk ^ (rrow & 15)) << 3)];
            *(uint4*)&Vt[((size_t)(b * NH + h) * HDK + dk) * SEQ + ss] = v;
        }
    }
}

// ---------------------------------------------------------------------------
// Kernel 2 (fallback, small workspace): fp32 A staged raw, converted in-loop.
// ---------------------------------------------------------------------------
__global__ __launch_bounds__(256) void qkv_gemm4(
    const float* __restrict__ Aq, const float* __restrict__ Ak,
    const float* __restrict__ Av, const unsigned short* __restrict__ Wt,
    const float* __restrict__ bq, const float* __restrict__ bk,
    const float* __restrict__ bv,
    unsigned short* __restrict__ Qw, unsigned short* __restrict__ Kw,
    unsigned short* __restrict__ Vt) {
    __shared__ float As[128 * 64];
    __shared__ unsigned short Bs[128 * 64];
    int lin = blockIdx.x;
    int swz = (lin & 7) * 144 + (lin >> 3);
    int mat = swz / 384;
    int rr = swz - mat * 384;
    int mblk = rr / 6;
    int nblk = rr - mblk * 6;
    const float* A = (mat == 0) ? Aq : ((mat == 1) ? Ak : Av);
    const unsigned short* W = Wt + (size_t)mat * DMODEL * DMODEL;
    const float* bias = (mat == 0) ? bq : ((mat == 1) ? bk : bv);
    int m0 = mblk * 128;
    int n0 = nblk * 128;
    int tid = threadIdx.x;
    int lane = tid & 63, wv = tid >> 6;
    int wm = (wv & 1) * 64, wn = (wv >> 1) * 64;
    int lm = lane & 15, quad = lane >> 4;

    const float* aS[8];
    float* aD[8];
    #pragma unroll
    for (int i = 0; i < 8; ++i) {
        int g = i * 256 + tid;
        int R = g >> 4, S = g & 15, c = (S & 8) | ((S & 7) ^ (R & 7));
        aS[i] = A + (size_t)(m0 + R) * DMODEL + c * 4;
        aD[i] = &As[(i * 256 + wv * 64) * 4];
    }
    const unsigned short* bS[4];
    unsigned short* bD[4];
    #pragma unroll
    for (int i = 0; i < 4; ++i) {
        int g = i * 256 + tid;
        int R = g >> 3, S = g & 7, c = S ^ (R & 7);
        bS[i] = W + (size_t)(n0 + R) * DMODEL + c * 8;
        bD[i] = &Bs[(i * 256 + wv * 64) * 8];
    }

    f32x4 acc[4][4] = {};
    int sx = lm & 7;
    const bool swapC = (mat < 2);
    for (int kt = 0; kt < 12; ++kt) {
        __syncthreads();
        #pragma unroll
        for (int i = 0; i < 8; ++i) lds_dma16(aS[i], aD[i]);
        #pragma unroll
        for (int i = 0; i < 4; ++i) lds_dma16(bS[i], bD[i]);
        #pragma unroll
        for (int i = 0; i < 8; ++i) aS[i] += 64;
        #pragma unroll
        for (int i = 0; i < 4; ++i) bS[i] += 64;
        __syncthreads();
        #pragma unroll
        for (int ks = 0; ks < 2; ++ks) {
            bf16x8 af[4], bfr[4];
            #pragma unroll
            for (int i = 0; i < 4; ++i) {
                int r = wm + i * 16 + lm;
                int c0 = ks * 8 + quad * 2;
                int s0 = (c0 & 8) | ((c0 & 7) ^ sx);
                int s1 = (c0 & 8) | (((c0 + 1) & 7) ^ sx);
                f32x4 lo = *(const f32x4*)&As[r * 64 + s0 * 4];
                f32x4 hi = *(const f32x4*)&As[r * 64 + s1 * 4];
                unsigned* au = (unsigned*)&af[i];
                au[0] = pack2bf(lo[0], lo[1]);
                au[1] = pack2bf(lo[2], lo[3]);
                au[2] = pack2bf(hi[0], hi[1]);
                au[3] = pack2bf(hi[2], hi[3]);
            }
            #pragma unroll
            for (int j = 0; j < 4; ++j)
                bfr[j] = *(const bf16x8*)&Bs[(wn + j * 16 + lm) * 64 +
                                             (((ks * 4 + quad) ^ sx) << 3)];
            if (swapC) {
                #pragma unroll
                for (int i = 0; i < 4; ++i)
                    #pragma unroll
                    for (int j = 0; j < 4; ++j)
                        acc[i][j] = __builtin_amdgcn_mfma_f32_16x16x32_bf16(
                            bfr[j], af[i], acc[i][j], 0, 0, 0);
            } else {
                #pragma unroll
                for (int i = 0; i < 4; ++i)
                    #pragma unroll
                    for (int j = 0; j < 4; ++j)
                        acc[i][j] = __builtin_amdgcn_mfma_f32_16x16x32_bf16(
                            af[i], bfr[j], acc[i][j], 0, 0, 0);
            }
        }
    }
    if (swapC) {
        float sc = (mat == 0) ? QSCALE : 1.0f;
        unsigned short* outp = (mat == 0) ? Qw : Kw;
        #pragma unroll
        for (int j = 0; j < 4; ++j) {
            int nbase = n0 + wn + j * 16 + quad * 4;
            f32x4 bvv = *(const f32x4*)&bias[nbase];
            int h = nbase >> 6, dk = nbase & 63;
            #pragma unroll
            for (int i = 0; i < 4; ++i) {
                int s = m0 + wm + i * 16 + lm;
                int b = s >> 12, ss = s & 4095;
                s16x4 o;
                #pragma unroll
                for (int r = 0; r < 4; ++r)
                    o[r] = (short)f2bf((acc[i][j][r] + bvv[r]) * sc);
                *(s16x4*)&outp[((size_t)(b * NH + h) * SEQ + ss) * HDK + dk] = o;
            }
        }
    } else {
        #pragma unroll
        for (int j = 0; j < 4; ++j) {
            int n = n0 + wn + j * 16 + lm;
            float bvv = bias[n];
            int h = n >> 6, dk = n & 63;
            #pragma unroll
            for (int i = 0; i < 4; ++i) {
                int mg = m0 + wm + i * 16 + quad * 4;
                int b = mg >> 12, s = mg & 4095;
                s16x4 o;
                #pragma unroll
                for (int r = 0; r < 4; ++r) o[r] = (short)f2bf(acc[i][j][r] + bvv);
                *(s16x4*)&Vt[((size_t)(b * NH + h) * HDK + dk) * SEQ + s] = o;
            }
        }
    }
}

// ---------------------------------------------------------------------------
// Kernel 3: flash attention v8 = v7 shell (kv-split, KVBLK=64, dbuf K+V,
// one __syncthreads/tile, (256,3), grid 768 co-resident) + softmax VALU cut:
//  - NO fixed shift: p = exp2(score*log2e), p <= 16; a consistent scale
//    cancels exactly in O/l. Masked cols: adds = (1-m)*(-10000*log2e) ->
//    exp2 flushes to exact 0 (same scale for masked-in cols).
//  - per-tile all-ones flag (one __ballot during mask staging): fast path
//    skips the 32 adds + 4 adv LDS reads per wave-tile entirely.
// Counters said VALUBusy 53% > MfmaUtil 36.5% -> VALU-limited; this removes
// the largest removable VALU term. Mask!=1 inputs still correct (slow path).
// ---------------------------------------------------------------------------
__global__ __launch_bounds__(256, 3) void attn_kernel(
    const unsigned short* __restrict__ Qw, const unsigned short* __restrict__ Kw,
    const unsigned short* __restrict__ Vt, const float* __restrict__ mask,
    float* __restrict__ out) {
    __shared__ __align__(16) char smem[33792];
    unsigned short* KsB = (unsigned short*)smem;            // [2][4096] shorts
    unsigned short* VsB = (unsigned short*)(smem + 16384);  // [2][4096] shorts
    float* addsB = (float*)(smem + 32768);                  // [2][64]
    int* flagB = (int*)(smem + 33280);                      // [2] all-ones flags
    // epilogue reuses smem as float fb[2][4224]

    int lin = blockIdx.x;
    int swz = (lin & 7) * 96 + (lin >> 3);      // 768 % 8 == 0 -> bijective
    int q0 = (swz & 31) * 128;
    int bh = swz >> 5;                          // 3 bh per XCD chunk
    int b = bh / NH, h = bh % NH;
    const unsigned short* Qb = Qw + (size_t)bh * SEQ * HDK;
    const char* Kb8 = (const char*)(Kw + (size_t)bh * SEQ * HDK);
    const char* Vb8 = (const char*)(Vt + (size_t)bh * HDK * SEQ);
    const float* mb = mask + (size_t)b * SEQ;
    int tid = threadIdx.x;
    int lane = tid & 63, wv = tid >> 6;         // 4 waves
    int qg = wv >> 1, kvh = wv & 1;
    int L31 = lane & 31, hh = lane >> 5;
    const int sx7 = L31 & 7;

    // Q fragments for both 32-row q-groups of this wave's 64-q span
    int qrow = q0 + qg * 64 + L31;
    bf16x8 qa[4], qbv[4];
    #pragma unroll
    for (int t = 0; t < 4; ++t) {
        qa[t] = *(const bf16x8*)&Qb[(size_t)qrow * HDK + t * 16 + hh * 8];
        qbv[t] = *(const bf16x8*)&Qb[(size_t)(qrow + 32) * HDK + t * 16 + hh * 8];
    }

    // 32-bit per-lane DMA offsets; 2 K-chunks + 2 V-chunks per wave (cc 0..7)
    unsigned koff[2], voff[2];
    #pragma unroll
    for (int i = 0; i < 2; ++i) {
        int cc = wv * 2 + i;
        {
            int rho = cc * 8 + (lane >> 3);     // 0..63
            int blk = rho >> 5, c = (rho >> 3) & 3, hb = (rho >> 2) & 1, r2 = rho & 3;
            int kc = blk * 32 + (c & 1) * 16 + hb * 8 + (c >> 1) * 4 + r2;
            int ch = (lane & 7) ^ (rho & 7);
            koff[i] = (unsigned)((kc * HDK + ch * 8) * 2);
        }
        {
            int d = cc * 8 + (lane >> 3);       // 0..63
            int c = lane & 7;
            int ch = c ^ (d & 7);
            voff[i] = (unsigned)((d * SEQ + ch * 8) * 2);
        }
    }

    // mask: adds/flag for tile 0; mnext carries tile kt+1's value (wave 0)
    float mnext = 0.0f;
    if (tid < 64) {
        float m0v = mb[tid];
        addsB[tid] = (1.0f - m0v) * (-10000.0f * LOG2E);
        unsigned long long bb = __ballot(m0v != 1.0f);
        if (tid == 0) flagB[0] = (bb == 0ULL);
        mnext = mb[64 + tid];
    }
    // prologue: stage K(0), V(0)
    #pragma unroll
    for (int i = 0; i < 2; ++i) {
        lds_dma16(Kb8 + koff[i], KsB + (wv * 2 + i) * 512);
        lds_dma16(Vb8 + voff[i], VsB + (wv * 2 + i) * 512);
    }
    __syncthreads();

    f32x16 Oa[2] = {}, Ob[2] = {};
    float lpa = 0.0f, lpb = 0.0f;
    const f32x16 kZero = {};
    const int blk = kvh;                         // this wave's 32-kv half

    for (int kt = 0; kt < 64; ++kt) {
        int cur = kt & 1;
        const unsigned short* Kc = KsB + cur * 4096;
        const unsigned short* Vc = VsB + cur * 4096;
        const float* adc = addsB + cur * 64;
        int fastf = flagB[cur];
        // prefetch kt+1 (covered by this tile's compute; drained by the sync)
        if (kt < 63) {
            const char* Kt8 = Kb8 + (size_t)(kt + 1) * 8192;
            const char* Vt8 = Vb8 + (size_t)(kt + 1) * 128;
            unsigned short* kd = KsB + (cur ^ 1) * 4096;
            unsigned short* vd = VsB + (cur ^ 1) * 4096;
            #pragma unroll
            for (int i = 0; i < 2; ++i) {
                lds_dma16(Kt8 + koff[i], kd + (wv * 2 + i) * 512);
                lds_dma16(Vt8 + voff[i], vd + (wv * 2 + i) * 512);
            }
        }
        if (tid < 64) {
            addsB[(cur ^ 1) * 64 + tid] = (1.0f - mnext) * (-10000.0f * LOG2E);
            unsigned long long bb = __ballot(mnext != 1.0f);
            if (tid == 0) flagB[cur ^ 1] = (bb == 0ULL);
            int mi = (kt < 62) ? (kt + 2) * 64 + tid : tid;
            mnext = mb[mi];
        }

        // S^T 32x32: A = K_perm rows [32blk..), B = Q; kf feeds both q-groups
        f32x16 sa, sb;
        __builtin_amdgcn_s_setprio(1);
        {
            bf16x8 kf = *(const bf16x8*)&Kc[(blk * 32 + L31) * 64 +
                                            ((hh ^ sx7) << 3)];
            sa = __builtin_amdgcn_mfma_f32_32x32x16_bf16(kf, qa[0], kZero, 0, 0, 0);
            sb = __builtin_amdgcn_mfma_f32_32x32x16_bf16(kf, qbv[0], kZero, 0, 0, 0);
        }
        #pragma unroll
        for (int t = 1; t < 4; ++t) {
            bf16x8 kf = *(const bf16x8*)&Kc[(blk * 32 + L31) * 64 +
                                            (((2 * t + hh) ^ sx7) << 3)];
            sa = __builtin_amdgcn_mfma_f32_32x32x16_bf16(kf, qa[t], sa, 0, 0, 0);
            sb = __builtin_amdgcn_mfma_f32_32x32x16_bf16(kf, qbv[t], sb, 0, 0, 0);
        }
        __builtin_amdgcn_s_setprio(0);

        // softmax; l accumulated in f32; fast path when tile mask is all-ones
        unsigned pkkA[2][4], pkkB[2][4];
        if (fastf) {
            #pragma unroll
            for (int c2 = 0; c2 < 4; ++c2) {
                float a0 = __builtin_amdgcn_exp2f(sa[c2 * 4 + 0]);
                float a1 = __builtin_amdgcn_exp2f(sa[c2 * 4 + 1]);
                float a2 = __builtin_amdgcn_exp2f(sa[c2 * 4 + 2]);
                float a3 = __builtin_amdgcn_exp2f(sa[c2 * 4 + 3]);
                lpa += (a0 + a1) + (a2 + a3);
                pkkA[c2 & 1][2 * (c2 >> 1) + 0] = pack2bf_t(a0, a1);
                pkkA[c2 & 1][2 * (c2 >> 1) + 1] = pack2bf_t(a2, a3);
                float b0v = __builtin_amdgcn_exp2f(sb[c2 * 4 + 0]);
                float b1v = __builtin_amdgcn_exp2f(sb[c2 * 4 + 1]);
                float b2v = __builtin_amdgcn_exp2f(sb[c2 * 4 + 2]);
                float b3v = __builtin_amdgcn_exp2f(sb[c2 * 4 + 3]);
                lpb += (b0v + b1v) + (b2v + b3v);
                pkkB[c2 & 1][2 * (c2 >> 1) + 0] = pack2bf_t(b0v, b1v);
                pkkB[c2 & 1][2 * (c2 >> 1) + 1] = pack2bf_t(b2v, b3v);
            }
        } else {
            #pragma unroll
            for (int c2 = 0; c2 < 4; ++c2) {
                f32x4 adv = *(const f32x4*)&adc[blk * 32 + (c2 & 1) * 16 +
                                                (c2 >> 1) * 4 + hh * 8];
                float a0 = __builtin_amdgcn_exp2f(sa[c2 * 4 + 0] + adv[0]);
                float a1 = __builtin_amdgcn_exp2f(sa[c2 * 4 + 1] + adv[1]);
                float a2 = __builtin_amdgcn_exp2f(sa[c2 * 4 + 2] + adv[2]);
                float a3 = __builtin_amdgcn_exp2f(sa[c2 * 4 + 3] + adv[3]);
                lpa += (a0 + a1) + (a2 + a3);
                pkkA[c2 & 1][2 * (c2 >> 1) + 0] = pack2bf_t(a0, a1);
                pkkA[c2 & 1][2 * (c2 >> 1) + 1] = pack2bf_t(a2, a3);
                float b0v = __builtin_amdgcn_exp2f(sb[c2 * 4 + 0] + adv[0]);
                float b1v = __builtin_amdgcn_exp2f(sb[c2 * 4 + 1] + adv[1]);
                float b2v = __builtin_amdgcn_exp2f(sb[c2 * 4 + 2] + adv[2]);
                float b3v = __builtin_amdgcn_exp2f(sb[c2 * 4 + 3] + adv[3]);
                lpb += (b0v + b1v) + (b2v + b3v);
                pkkB[c2 & 1][2 * (c2 >> 1) + 0] = pack2bf_t(b0v, b1v);
                pkkB[c2 & 1][2 * (c2 >> 1) + 1] = pack2bf_t(b2v, b3v);
            }
        }

        // O^T += V^T . P^T for this wave's kv-half
        __builtin_amdgcn_s_setprio(1);
        #pragma unroll
        for (int kbi = 0; kbi < 2; ++kbi) {
            bf16x8 pfA, pfB;
            unsigned* pa = (unsigned*)&pfA;
            unsigned* pb = (unsigned*)&pfB;
            pa[0] = pkkA[kbi][0]; pa[1] = pkkA[kbi][1];
            pa[2] = pkkA[kbi][2]; pa[3] = pkkA[kbi][3];
            pb[0] = pkkB[kbi][0]; pb[1] = pkkB[kbi][1];
            pb[2] = pkkB[kbi][2]; pb[3] = pkkB[kbi][3];
            int kb = blk * 2 + kbi;
            #pragma unroll
            for (int dj = 0; dj < 2; ++dj) {
                int c = kb * 2 + hh;                 // 0..7
                int slot = c ^ (lane & 7);
                bf16x8 vf = *(const bf16x8*)&Vc[(dj * 32 + L31) * 64 + slot * 8];
                Oa[dj] = __builtin_amdgcn_mfma_f32_32x32x16_bf16(vf, pfA, Oa[dj], 0, 0, 0);
                Ob[dj] = __builtin_amdgcn_mfma_f32_32x32x16_bf16(vf, pfB, Ob[dj], 0, 0, 0);
            }
        }
        __builtin_amdgcn_s_setprio(0);
        __syncthreads();
    }

    // combine hh halves of l within the wave
    lpa += __shfl_xor(lpa, 32);
    lpb += __shfl_xor(lpb, 32);

    // cross-wave (kv-half pair) reduction through the dead K/V LDS.
    float* fb = (float*)smem + qg * 4224;
    if (kvh == 0) {
        #pragma unroll
        for (int dj = 0; dj < 2; ++dj)
            #pragma unroll
            for (int e = 0; e < 16; ++e) {
                fb[(dj * 16 + e) * 64 + lane] = Oa[dj][e];
                fb[(32 + dj * 16 + e) * 64 + lane] = Ob[dj][e];
            }
        fb[4096 + lane] = lpa;
        fb[4160 + lane] = lpb;
    }
    __syncthreads();
    if (kvh == 1) {
        #pragma unroll
        for (int dj = 0; dj < 2; ++dj)
            #pragma unroll
            for (int e = 0; e < 16; ++e) {
                Oa[dj][e] += fb[(dj * 16 + e) * 64 + lane];
                Ob[dj][e] += fb[(32 + dj * 16 + e) * 64 + lane];
            }
        float rla = 1.0f / (lpa + fb[4096 + lane]);
        float rlb = 1.0f / (lpb + fb[4160 + lane]);
        size_t basea = ((size_t)b * SEQ + qrow) * DMODEL + h * HDK;
        #pragma unroll
        for (int dj = 0; dj < 2; ++dj)
            #pragma unroll
            for (int c2 = 0; c2 < 4; ++c2) {
                int d = dj * 32 + 8 * c2 + 4 * hh;
                float4 o;
                o.x = Oa[dj][c2 * 4 + 0] * rla;
                o.y = Oa[dj][c2 * 4 + 1] * rla;
                o.z = Oa[dj][c2 * 4 + 2] * rla;
                o.w = Oa[dj][c2 * 4 + 3] * rla;
                *(float4*)&out[basea + d] = o;
                float4 o2;
                o2.x = Ob[dj][c2 * 4 + 0] * rlb;
                o2.y = Ob[dj][c2 * 4 + 1] * rlb;
                o2.z = Ob[dj][c2 * 4 + 2] * rlb;
                o2.w = Ob[dj][c2 * 4 + 3] * rlb;
                *(float4*)&out[basea + (size_t)32 * DMODEL + d] = o2;
            }
    }
}

// ---------------------------------------------------------------------------
extern "C" void kernel_launch(void* const* d_in, const int* in_sizes, int n_in,
                              void* d_out, int out_size, void* d_ws, size_t ws_size,
                              hipStream_t stream) {
    (void)in_sizes; (void)n_in; (void)out_size;
    const float* query = (const float*)d_in[0];
    const float* key   = (const float*)d_in[1];
    const float* value = (const float*)d_in[2];
    const float* mask  = (const float*)d_in[3];
    const float* Wq    = (const float*)d_in[4];
    const float* bq    = (const float*)d_in[5];
    const float* Wk    = (const float*)d_in[6];
    const float* bk    = (const float*)d_in[7];
    const float* Wv    = (const float*)d_in[8];
    const float* bv    = (const float*)d_in[9];

    const size_t WT_BYTES  = (size_t)3 * DMODEL * DMODEL * 2;       //  3.5 MB
    const size_t ABF_BYTES = (size_t)3 * NB * SEQ * DMODEL * 2;     // 37.7 MB
    const size_t QKV_BYTES = (size_t)NB * NH * SEQ * HDK * 2;       // 12.6 MB

    unsigned short* Wt = (unsigned short*)d_ws;
    if (ws_size >= WT_BYTES + ABF_BYTES + 3 * QKV_BYTES) {
        unsigned short* Abf = (unsigned short*)((char*)d_ws + WT_BYTES);
        unsigned short* Qw = (unsigned short*)((char*)d_ws + WT_BYTES + ABF_BYTES);
        unsigned short* Kw = (unsigned short*)((char*)d_ws + WT_BYTES + ABF_BYTES + QKV_BYTES);
        unsigned short* Vt = (unsigned short*)((char*)d_ws + WT_BYTES + ABF_BYTES + 2 * QKV_BYTES);
        wt_kernel<<<dim3(24, 24, 3), 256, 0, stream>>>(Wq, Wk, Wv, Wt);
        abf_kernel<<<dim3(768, 3), 256, 0, stream>>>(query, key, value, Abf);
        qkv_gemm8<<<dim3(1152), 256, 0, stream>>>(Abf, Wt, bq, bk, bv, Qw, Kw, Vt);
        attn_kernel<<<dim3(768), 256, 0, stream>>>(Qw, Kw, Vt, mask, (float*)d_out);
    } else {
        unsigned short* Qw = (unsigned short*)((char*)d_ws + WT_BYTES);
        unsigned short* Kw = (unsigned short*)((char*)d_ws + WT_BYTES + QKV_BYTES);
        unsigned short* Vt = (unsigned short*)((char*)d_ws + WT_BYTES + 2 * QKV_BYTES);
        wt_kernel<<<dim3(24, 24, 3), 256, 0, stream>>>(Wq, Wk, Wv, Wt);
        qkv_gemm4<<<dim3(1152), 256, 0, stream>>>(query, key, value, Wt,
                                                  bq, bk, bv, Qw, Kw, Vt);
        attn_kernel<<<dim3(768), 256, 0, stream>>>(Qw, Kw, Vt, mask, (float*)d_out);
    }
}

// Round 8
// 333.672 us; speedup vs baseline: 1.1544x; 1.1544x over previous
//
#include <hip/hip_runtime.h>
#include <stdint.h>

#define NH 12
#define DMODEL 768
#define HDK 64
#define SEQ 4096
#define NB 2

typedef __attribute__((ext_vector_type(8))) short bf16x8;
typedef __attribute__((ext_vector_type(4))) short s16x4;
typedef __attribute__((ext_vector_type(4))) float f32x4;
typedef __attribute__((ext_vector_type(16))) float f32x16;

#define LOG2E 1.44269504f
#define QSCALE 0.18033688f   /* 0.125 * log2(e), folded into Q at projection */
#define CSUB 4.0f            /* fixed softmax shift; |score*log2e| < 4 */
/* Round-7 lesson: a runtime branch inside the unrolled softmax loop caused
   register-join pressure + broken scheduling (125->232us). Softmax stays
   straight-line with the +adv add. */

__device__ __forceinline__ unsigned short f2bf(float x) {
    union { float f; unsigned u; } v; v.f = x;
    unsigned r = v.u + 0x7FFFu + ((v.u >> 16) & 1u);
    return (unsigned short)(r >> 16);
}

// pack two fp32 -> two bf16, round-half-up (2 add + 1 perm)
__device__ __forceinline__ unsigned pack2bf(float a, float b) {
    union { float f; unsigned u; } x, y; x.f = a; y.f = b;
    return __builtin_amdgcn_perm(y.u + 0x8000u, x.u + 0x8000u, 0x07060302u);
}

// pack two fp32 -> two bf16, TRUNCATING (1 perm); P only (bias cancels in ratio)
__device__ __forceinline__ unsigned pack2bf_t(float a, float b) {
    union { float f; unsigned u; } x, y; x.f = a; y.f = b;
    return __builtin_amdgcn_perm(y.u, x.u, 0x07060302u);
}

// async global -> LDS: dest = wave-uniform base + lane*16
__device__ __forceinline__ void lds_dma16(const void* g, void* l) {
    __builtin_amdgcn_global_load_lds(
        (const __attribute__((address_space(1))) void*)g,
        (__attribute__((address_space(3))) void*)l, 16, 0, 0);
}

// ---------------------------------------------------------------------------
// Kernel 1: W [k][n] fp32 -> Wt [n][k] bf16
// ---------------------------------------------------------------------------
__global__ __launch_bounds__(256) void wt_kernel(
    const float* __restrict__ Wq, const float* __restrict__ Wk,
    const float* __restrict__ Wv, unsigned short* __restrict__ Wt) {
    __shared__ float ts[32][33];
    int mat = blockIdx.z;
    const float* W = (mat == 0) ? Wq : ((mat == 1) ? Wk : Wv);
    unsigned short* out = Wt + (size_t)mat * DMODEL * DMODEL;
    int k0 = blockIdx.x * 32;
    int n0 = blockIdx.y * 32;
    int t = threadIdx.x;
    int row = t >> 3, c4 = (t & 7) * 4;
    float4 v = *(const float4*)&W[(size_t)(k0 + row) * DMODEL + n0 + c4];
    ts[row][c4 + 0] = v.x; ts[row][c4 + 1] = v.y;
    ts[row][c4 + 2] = v.z; ts[row][c4 + 3] = v.w;
    __syncthreads();
    s16x4 o;
    o[0] = (short)f2bf(ts[c4 + 0][row]);
    o[1] = (short)f2bf(ts[c4 + 1][row]);
    o[2] = (short)f2bf(ts[c4 + 2][row]);
    o[3] = (short)f2bf(ts[c4 + 3][row]);
    *(s16x4*)&out[(size_t)(n0 + row) * DMODEL + k0 + c4] = o;
}

// ---------------------------------------------------------------------------
// Kernel 1b: A fp32 [3][8192][768] -> bf16, one-shot (BW-bound pre-pass).
// ---------------------------------------------------------------------------
__global__ __launch_bounds__(256) void abf_kernel(
    const float* __restrict__ Aq, const float* __restrict__ Ak,
    const float* __restrict__ Av, unsigned short* __restrict__ Abf) {
    int mat = blockIdx.y;
    const float* A = (mat == 0) ? Aq : ((mat == 1) ? Ak : Av);
    unsigned short* o = Abf + (size_t)mat * NB * SEQ * DMODEL;
    int t = blockIdx.x * 256 + threadIdx.x;
    #pragma unroll
    for (int i = 0; i < 4; ++i) {
        size_t e = ((size_t)i * 196608 + t) * 8;   // 768*256*32 = 6291456 elems
        float4 lo = *(const float4*)&A[e];
        float4 hi = *(const float4*)&A[e + 4];
        uint4 r;
        r.x = pack2bf(lo.x, lo.y); r.y = pack2bf(lo.z, lo.w);
        r.z = pack2bf(hi.x, hi.y); r.w = pack2bf(hi.z, hi.w);
        *(uint4*)&o[e] = r;
    }
}

// ---------------------------------------------------------------------------
// Kernel 2 (primary): QKV GEMM v9 = gemm8 data path + TRIPLE-buffer depth-2
// prefetch with counted vmcnt. gemm8's end-of-body __syncthreads drained
// vmcnt(0) giving each prefetch only the ~250cyc MFMA phase of cover -> every
// kt ate L2 latency. Now: iter kt reads buf[kt%3], issues DMA into
// buf[(kt+2)%3] (= buffer read at kt-1, protected by kt-1's lgkmcnt+barrier),
// waits vmcnt(8) (kt's 4 done; kt+1/kt+2's 8 stay in flight ACROSS barriers).
// Loads get ~2 full iterations of cover. LDS 48KB -> still 3 blocks/CU.
// Coalesced LDS-transposed epilogue unchanged (tile aliases the buffers).
// ---------------------------------------------------------------------------
__global__ __launch_bounds__(256, 3) void qkv_gemm9(
    const unsigned short* __restrict__ Abf, const unsigned short* __restrict__ Wt,
    const float* __restrict__ bq, const float* __restrict__ bk,
    const float* __restrict__ bv,
    unsigned short* __restrict__ Qw, unsigned short* __restrict__ Kw,
    unsigned short* __restrict__ Vt) {
    __shared__ __align__(16) char smem[49152];
    unsigned short* AsB = (unsigned short*)smem;            // [3][4096] shorts
    unsigned short* BsB = (unsigned short*)(smem + 24576);  // [3][4096] shorts
    unsigned short* T   = (unsigned short*)smem;            // epilogue [128][128]

    int lin = blockIdx.x;
    int swz = (lin & 7) * 144 + (lin >> 3);   // XCD-chunked (1152 % 8 == 0)
    int mat = swz / 384;
    int rr = swz - mat * 384;
    int mblk = rr / 6;
    int nblk = rr - mblk * 6;                 // n fastest: A-panel sharers adjacent
    const unsigned short* A = Abf + (size_t)mat * NB * SEQ * DMODEL;
    const unsigned short* W = Wt + (size_t)mat * DMODEL * DMODEL;
    const float* bias = (mat == 0) ? bq : ((mat == 1) ? bk : bv);
    int m0 = mblk * 128;
    int n0 = nblk * 128;
    int tid = threadIdx.x;
    int lane = tid & 63, wv = tid >> 6;
    int wm = (wv & 1) * 64, wn = (wv >> 1) * 64;
    int lm = lane & 15, quad = lane >> 4;

    const unsigned short* aS[2];
    const unsigned short* bS[2];
    #pragma unroll
    for (int i = 0; i < 2; ++i) {
        int g = i * 256 + tid;
        int R = g >> 2, c = g & 3, ch = c ^ (R & 3);
        aS[i] = A + (size_t)(m0 + R) * DMODEL + ch * 8;
        bS[i] = W + (size_t)(n0 + R) * DMODEL + ch * 8;
    }

    f32x4 acc[4][4] = {};
    const int sx3 = lm & 3;
    const bool swapC = (mat < 2);

    // prologue: stage kt=0 -> buf0, kt=1 -> buf1
    #pragma unroll
    for (int i = 0; i < 2; ++i) {
        lds_dma16(aS[i], AsB + (i * 256 + wv * 64) * 8);
        lds_dma16(bS[i], BsB + (i * 256 + wv * 64) * 8);
        aS[i] += 32; bS[i] += 32;
    }
    #pragma unroll
    for (int i = 0; i < 2; ++i) {
        lds_dma16(aS[i], AsB + 4096 + (i * 256 + wv * 64) * 8);
        lds_dma16(bS[i], BsB + 4096 + (i * 256 + wv * 64) * 8);
        aS[i] += 32; bS[i] += 32;
    }

    int cur = 0;
    for (int kt = 0; kt < 24; ++kt) {
        if (kt < 22) {
            int nxt = cur + 2; if (nxt >= 3) nxt -= 3;   // (kt+2) % 3
            unsigned short* ad = AsB + nxt * 4096;
            unsigned short* bd = BsB + nxt * 4096;
            #pragma unroll
            for (int i = 0; i < 2; ++i) {
                lds_dma16(aS[i], ad + (i * 256 + wv * 64) * 8);
                lds_dma16(bS[i], bd + (i * 256 + wv * 64) * 8);
                aS[i] += 32; bS[i] += 32;
            }
            asm volatile("s_waitcnt vmcnt(8)" ::: "memory");
        } else if (kt == 22) {
            asm volatile("s_waitcnt vmcnt(4)" ::: "memory");
        } else {
            asm volatile("s_waitcnt vmcnt(0)" ::: "memory");
        }
        __builtin_amdgcn_s_barrier();   // kt's tile visible to all waves

        const unsigned short* Ac = AsB + cur * 4096;
        const unsigned short* Bc = BsB + cur * 4096;
        bf16x8 af[4], bfr[4];
        #pragma unroll
        for (int i = 0; i < 4; ++i)
            af[i] = *(const bf16x8*)&Ac[(wm + i * 16 + lm) * 32 +
                                        ((quad ^ sx3) << 3)];
        #pragma unroll
        for (int j = 0; j < 4; ++j)
            bfr[j] = *(const bf16x8*)&Bc[(wn + j * 16 + lm) * 32 +
                                         ((quad ^ sx3) << 3)];
        if (swapC) {
            #pragma unroll
            for (int i = 0; i < 4; ++i)
                #pragma unroll
                for (int j = 0; j < 4; ++j)
                    acc[i][j] = __builtin_amdgcn_mfma_f32_16x16x32_bf16(
                        bfr[j], af[i], acc[i][j], 0, 0, 0);
        } else {
            #pragma unroll
            for (int i = 0; i < 4; ++i)
                #pragma unroll
                for (int j = 0; j < 4; ++j)
                    acc[i][j] = __builtin_amdgcn_mfma_f32_16x16x32_bf16(
                        af[i], bfr[j], acc[i][j], 0, 0, 0);
        }
        asm volatile("s_waitcnt lgkmcnt(0)" ::: "memory");  // reads retired
        __builtin_amdgcn_s_barrier();   // next iter's DMA overwrites buf cur
        cur = cur + 1; if (cur >= 3) cur -= 3;
    }

    // ---- epilogue phase 1: bias+scale+pack into LDS tile (swizzled) ----
    if (swapC) {
        float sc = (mat == 0) ? QSCALE : 1.0f;
        #pragma unroll
        for (int j = 0; j < 4; ++j) {
            int nb = wn + j * 16 + quad * 4;
            f32x4 bvv = *(const f32x4*)&bias[n0 + nb];
            #pragma unroll
            for (int i = 0; i < 4; ++i) {
                int s = wm + i * 16 + lm;
                s16x4 o;
                #pragma unroll
                for (int r = 0; r < 4; ++r)
                    o[r] = (short)f2bf((acc[i][j][r] + bvv[r]) * sc);
                int idx = s * 128 + ((((nb >> 3) ^ (s & 15)) << 3) | (nb & 7));
                *(s16x4*)&T[idx] = o;
            }
        }
    } else {
        #pragma unroll
        for (int j = 0; j < 4; ++j) {
            int n = wn + j * 16 + lm;
            float bvv = bias[n0 + n];
            #pragma unroll
            for (int i = 0; i < 4; ++i) {
                int mg = wm + i * 16 + quad * 4;
                s16x4 o;
                #pragma unroll
                for (int r = 0; r < 4; ++r) o[r] = (short)f2bf(acc[i][j][r] + bvv);
                int idx = n * 128 + ((((mg >> 3) ^ (n & 15)) << 3) | (mg & 7));
                *(s16x4*)&T[idx] = o;
            }
        }
    }
    __syncthreads();

    // ---- epilogue phase 2: coalesced readout (8 x 16B per thread) ----
    int row8 = tid >> 4, chunk = tid & 15;
    if (swapC) {
        unsigned short* outp = (mat == 0) ? Qw : Kw;
        int n = chunk * 8;
        int h = (n0 + n) >> 6, dk = (n0 + n) & 63;
        #pragma unroll
        for (int it = 0; it < 8; ++it) {
            int rrow = it * 16 + row8;
            int s = m0 + rrow;
            int b = s >> 12, ss = s & 4095;
            uint4 v = *(const uint4*)&T[rrow * 128 +
                                        ((chunk ^ (rrow & 15)) << 3)];
            *(uint4*)&outp[((size_t)(b * NH + h) * SEQ + ss) * HDK + dk] = v;
        }
    } else {
        int s = m0 + chunk * 8;
        int b = s >> 12, ss = s & 4095;
        #pragma unroll
        for (int it = 0; it < 8; ++it) {
            int rrow = it * 16 + row8;
            int dk = (n0 + rrow) & 63, h = (n0 + rrow) >> 6;
            uint4 v = *(const uint4*)&T[rrow * 128 +
                                        ((chunk ^ (rrow & 15)) << 3)];
            *(uint4*)&Vt[((size_t)(b * NH + h) * HDK + dk) * SEQ + ss] = v;
        }
    }
}

// ---------------------------------------------------------------------------
// Kernel 2 (fallback, small workspace): fp32 A staged raw, converted in-loop.
// ---------------------------------------------------------------------------
__global__ __launch_bounds__(256) void qkv_gemm4(
    const float* __restrict__ Aq, const float* __restrict__ Ak,
    const float* __restrict__ Av, const unsigned short* __restrict__ Wt,
    const float* __restrict__ bq, const float* __restrict__ bk,
    const float* __restrict__ bv,
    unsigned short* __restrict__ Qw, unsigned short* __restrict__ Kw,
    unsigned short* __restrict__ Vt) {
    __shared__ float As[128 * 64];
    __shared__ unsigned short Bs[128 * 64];
    int lin = blockIdx.x;
    int swz = (lin & 7) * 144 + (lin >> 3);
    int mat = swz / 384;
    int rr = swz - mat * 384;
    int mblk = rr / 6;
    int nblk = rr - mblk * 6;
    const float* A = (mat == 0) ? Aq : ((mat == 1) ? Ak : Av);
    const unsigned short* W = Wt + (size_t)mat * DMODEL * DMODEL;
    const float* bias = (mat == 0) ? bq : ((mat == 1) ? bk : bv);
    int m0 = mblk * 128;
    int n0 = nblk * 128;
    int tid = threadIdx.x;
    int lane = tid & 63, wv = tid >> 6;
    int wm = (wv & 1) * 64, wn = (wv >> 1) * 64;
    int lm = lane & 15, quad = lane >> 4;

    const float* aS[8];
    float* aD[8];
    #pragma unroll
    for (int i = 0; i < 8; ++i) {
        int g = i * 256 + tid;
        int R = g >> 4, S = g & 15, c = (S & 8) | ((S & 7) ^ (R & 7));
        aS[i] = A + (size_t)(m0 + R) * DMODEL + c * 4;
        aD[i] = &As[(i * 256 + wv * 64) * 4];
    }
    const unsigned short* bS[4];
    unsigned short* bD[4];
    #pragma unroll
    for (int i = 0; i < 4; ++i) {
        int g = i * 256 + tid;
        int R = g >> 3, S = g & 7, c = S ^ (R & 7);
        bS[i] = W + (size_t)(n0 + R) * DMODEL + c * 8;
        bD[i] = &Bs[(i * 256 + wv * 64) * 8];
    }

    f32x4 acc[4][4] = {};
    int sx = lm & 7;
    const bool swapC = (mat < 2);
    for (int kt = 0; kt < 12; ++kt) {
        __syncthreads();
        #pragma unroll
        for (int i = 0; i < 8; ++i) lds_dma16(aS[i], aD[i]);
        #pragma unroll
        for (int i = 0; i < 4; ++i) lds_dma16(bS[i], bD[i]);
        #pragma unroll
        for (int i = 0; i < 8; ++i) aS[i] += 64;
        #pragma unroll
        for (int i = 0; i < 4; ++i) bS[i] += 64;
        __syncthreads();
        #pragma unroll
        for (int ks = 0; ks < 2; ++ks) {
            bf16x8 af[4], bfr[4];
            #pragma unroll
            for (int i = 0; i < 4; ++i) {
                int r = wm + i * 16 + lm;
                int c0 = ks * 8 + quad * 2;
                int s0 = (c0 & 8) | ((c0 & 7) ^ sx);
                int s1 = (c0 & 8) | (((c0 + 1) & 7) ^ sx);
                f32x4 lo = *(const f32x4*)&As[r * 64 + s0 * 4];
                f32x4 hi = *(const f32x4*)&As[r * 64 + s1 * 4];
                unsigned* au = (unsigned*)&af[i];
                au[0] = pack2bf(lo[0], lo[1]);
                au[1] = pack2bf(lo[2], lo[3]);
                au[2] = pack2bf(hi[0], hi[1]);
                au[3] = pack2bf(hi[2], hi[3]);
            }
            #pragma unroll
            for (int j = 0; j < 4; ++j)
                bfr[j] = *(const bf16x8*)&Bs[(wn + j * 16 + lm) * 64 +
                                             (((ks * 4 + quad) ^ sx) << 3)];
            if (swapC) {
                #pragma unroll
                for (int i = 0; i < 4; ++i)
                    #pragma unroll
                    for (int j = 0; j < 4; ++j)
                        acc[i][j] = __builtin_amdgcn_mfma_f32_16x16x32_bf16(
                            bfr[j], af[i], acc[i][j], 0, 0, 0);
            } else {
                #pragma unroll
                for (int i = 0; i < 4; ++i)
                    #pragma unroll
                    for (int j = 0; j < 4; ++j)
                        acc[i][j] = __builtin_amdgcn_mfma_f32_16x16x32_bf16(
                            af[i], bfr[j], acc[i][j], 0, 0, 0);
            }
        }
    }
    if (swapC) {
        float sc = (mat == 0) ? QSCALE : 1.0f;
        unsigned short* outp = (mat == 0) ? Qw : Kw;
        #pragma unroll
        for (int j = 0; j < 4; ++j) {
            int nbase = n0 + wn + j * 16 + quad * 4;
            f32x4 bvv = *(const f32x4*)&bias[nbase];
            int h = nbase >> 6, dk = nbase & 63;
            #pragma unroll
            for (int i = 0; i < 4; ++i) {
                int s = m0 + wm + i * 16 + lm;
                int b = s >> 12, ss = s & 4095;
                s16x4 o;
                #pragma unroll
                for (int r = 0; r < 4; ++r)
                    o[r] = (short)f2bf((acc[i][j][r] + bvv[r]) * sc);
                *(s16x4*)&outp[((size_t)(b * NH + h) * SEQ + ss) * HDK + dk] = o;
            }
        }
    } else {
        #pragma unroll
        for (int j = 0; j < 4; ++j) {
            int n = n0 + wn + j * 16 + lm;
            float bvv = bias[n];
            int h = n >> 6, dk = n & 63;
            #pragma unroll
            for (int i = 0; i < 4; ++i) {
                int mg = m0 + wm + i * 16 + quad * 4;
                int b = mg >> 12, s = mg & 4095;
                s16x4 o;
                #pragma unroll
                for (int r = 0; r < 4; ++r) o[r] = (short)f2bf(acc[i][j][r] + bvv);
                *(s16x4*)&Vt[((size_t)(b * NH + h) * HDK + dk) * SEQ + s] = o;
            }
        }
    }
}

// ---------------------------------------------------------------------------
// Kernel 3: flash attention — REVERTED to the round-6 kernel verbatim
// (measured 125.0us, MfmaUtil 36.5, VALUBusy 53, no spill). kv-split,
// KVBLK=64, dbuf K+V, one __syncthreads/tile, (256,3), grid 768 co-resident.
// ---------------------------------------------------------------------------
__global__ __launch_bounds__(256, 3) void attn_kernel(
    const unsigned short* __restrict__ Qw, const unsigned short* __restrict__ Kw,
    const unsigned short* __restrict__ Vt, const float* __restrict__ mask,
    float* __restrict__ out) {
    __shared__ __align__(16) char smem[33792];
    unsigned short* KsB = (unsigned short*)smem;            // [2][4096] shorts
    unsigned short* VsB = (unsigned short*)(smem + 16384);  // [2][4096] shorts
    float* addsB = (float*)(smem + 32768);                  // [2][64]
    // epilogue reuses smem as float fb[2][4224]

    int lin = blockIdx.x;
    int swz = (lin & 7) * 96 + (lin >> 3);      // 768 % 8 == 0 -> bijective
    int q0 = (swz & 31) * 128;
    int bh = swz >> 5;                          // 3 bh per XCD chunk
    int b = bh / NH, h = bh % NH;
    const unsigned short* Qb = Qw + (size_t)bh * SEQ * HDK;
    const char* Kb8 = (const char*)(Kw + (size_t)bh * SEQ * HDK);
    const char* Vb8 = (const char*)(Vt + (size_t)bh * HDK * SEQ);
    const float* mb = mask + (size_t)b * SEQ;
    int tid = threadIdx.x;
    int lane = tid & 63, wv = tid >> 6;         // 4 waves
    int qg = wv >> 1, kvh = wv & 1;
    int L31 = lane & 31, hh = lane >> 5;
    const int sx7 = L31 & 7;

    // Q fragments for both 32-row q-groups of this wave's 64-q span
    int qrow = q0 + qg * 64 + L31;
    bf16x8 qa[4], qbv[4];
    #pragma unroll
    for (int t = 0; t < 4; ++t) {
        qa[t] = *(const bf16x8*)&Qb[(size_t)qrow * HDK + t * 16 + hh * 8];
        qbv[t] = *(const bf16x8*)&Qb[(size_t)(qrow + 32) * HDK + t * 16 + hh * 8];
    }

    // 32-bit per-lane DMA offsets; 2 K-chunks + 2 V-chunks per wave (cc 0..7)
    unsigned koff[2], voff[2];
    #pragma unroll
    for (int i = 0; i < 2; ++i) {
        int cc = wv * 2 + i;
        {
            int rho = cc * 8 + (lane >> 3);     // 0..63
            int blk = rho >> 5, c = (rho >> 3) & 3, hb = (rho >> 2) & 1, r2 = rho & 3;
            int kc = blk * 32 + (c & 1) * 16 + hb * 8 + (c >> 1) * 4 + r2;
            int ch = (lane & 7) ^ (rho & 7);
            koff[i] = (unsigned)((kc * HDK + ch * 8) * 2);
        }
        {
            int d = cc * 8 + (lane >> 3);       // 0..63
            int c = lane & 7;
            int ch = c ^ (d & 7);
            voff[i] = (unsigned)((d * SEQ + ch * 8) * 2);
        }
    }

    // mask: adds[0] for tile 0; mnext carries tile kt+1's mask value (wave 0)
    float mnext = 0.0f;
    if (tid < 64) {
        addsB[tid] = ((1.0f - mb[tid]) * -10000.0f - CSUB) * LOG2E;
        mnext = mb[64 + tid];
    }
    // prologue: stage K(0), V(0)
    #pragma unroll
    for (int i = 0; i < 2; ++i) {
        lds_dma16(Kb8 + koff[i], KsB + (wv * 2 + i) * 512);
        lds_dma16(Vb8 + voff[i], VsB + (wv * 2 + i) * 512);
    }
    __syncthreads();

    f32x16 Oa[2] = {}, Ob[2] = {};
    float lpa = 0.0f, lpb = 0.0f;
    const f32x16 kZero = {};
    const int blk = kvh;                         // this wave's 32-kv half

    for (int kt = 0; kt < 64; ++kt) {
        int cur = kt & 1;
        const unsigned short* Kc = KsB + cur * 4096;
        const unsigned short* Vc = VsB + cur * 4096;
        const float* adc = addsB + cur * 64;
        // prefetch kt+1 (covered by this tile's compute; drained by the sync)
        if (kt < 63) {
            const char* Kt8 = Kb8 + (size_t)(kt + 1) * 8192;
            const char* Vt8 = Vb8 + (size_t)(kt + 1) * 128;
            unsigned short* kd = KsB + (cur ^ 1) * 4096;
            unsigned short* vd = VsB + (cur ^ 1) * 4096;
            #pragma unroll
            for (int i = 0; i < 2; ++i) {
                lds_dma16(Kt8 + koff[i], kd + (wv * 2 + i) * 512);
                lds_dma16(Vt8 + voff[i], vd + (wv * 2 + i) * 512);
            }
        }
        if (tid < 64) {
            addsB[(cur ^ 1) * 64 + tid] =
                ((1.0f - mnext) * -10000.0f - CSUB) * LOG2E;
            int mi = (kt < 62) ? (kt + 2) * 64 + tid : tid;
            mnext = mb[mi];
        }

        // S^T 32x32: A = K_perm rows [32blk..), B = Q; kf feeds both q-groups
        f32x16 sa, sb;
        __builtin_amdgcn_s_setprio(1);
        {
            bf16x8 kf = *(const bf16x8*)&Kc[(blk * 32 + L31) * 64 +
                                            ((hh ^ sx7) << 3)];
            sa = __builtin_amdgcn_mfma_f32_32x32x16_bf16(kf, qa[0], kZero, 0, 0, 0);
            sb = __builtin_amdgcn_mfma_f32_32x32x16_bf16(kf, qbv[0], kZero, 0, 0, 0);
        }
        #pragma unroll
        for (int t = 1; t < 4; ++t) {
            bf16x8 kf = *(const bf16x8*)&Kc[(blk * 32 + L31) * 64 +
                                            (((2 * t + hh) ^ sx7) << 3)];
            sa = __builtin_amdgcn_mfma_f32_32x32x16_bf16(kf, qa[t], sa, 0, 0, 0);
            sb = __builtin_amdgcn_mfma_f32_32x32x16_bf16(kf, qbv[t], sb, 0, 0, 0);
        }
        __builtin_amdgcn_s_setprio(0);

        // softmax; l accumulated in f32
        unsigned pkkA[2][4], pkkB[2][4];
        #pragma unroll
        for (int c2 = 0; c2 < 4; ++c2) {
            f32x4 adv = *(const f32x4*)&adc[blk * 32 + (c2 & 1) * 16 +
                                            (c2 >> 1) * 4 + hh * 8];
            float a0 = __builtin_amdgcn_exp2f(sa[c2 * 4 + 0] + adv[0]);
            float a1 = __builtin_amdgcn_exp2f(sa[c2 * 4 + 1] + adv[1]);
            float a2 = __builtin_amdgcn_exp2f(sa[c2 * 4 + 2] + adv[2]);
            float a3 = __builtin_amdgcn_exp2f(sa[c2 * 4 + 3] + adv[3]);
            lpa += (a0 + a1) + (a2 + a3);
            pkkA[c2 & 1][2 * (c2 >> 1) + 0] = pack2bf_t(a0, a1);
            pkkA[c2 & 1][2 * (c2 >> 1) + 1] = pack2bf_t(a2, a3);
            float b0v = __builtin_amdgcn_exp2f(sb[c2 * 4 + 0] + adv[0]);
            float b1v = __builtin_amdgcn_exp2f(sb[c2 * 4 + 1] + adv[1]);
            float b2v = __builtin_amdgcn_exp2f(sb[c2 * 4 + 2] + adv[2]);
            float b3v = __builtin_amdgcn_exp2f(sb[c2 * 4 + 3] + adv[3]);
            lpb += (b0v + b1v) + (b2v + b3v);
            pkkB[c2 & 1][2 * (c2 >> 1) + 0] = pack2bf_t(b0v, b1v);
            pkkB[c2 & 1][2 * (c2 >> 1) + 1] = pack2bf_t(b2v, b3v);
        }

        // O^T += V^T . P^T for this wave's kv-half
        __builtin_amdgcn_s_setprio(1);
        #pragma unroll
        for (int kbi = 0; kbi < 2; ++kbi) {
            bf16x8 pfA, pfB;
            unsigned* pa = (unsigned*)&pfA;
            unsigned* pb = (unsigned*)&pfB;
            pa[0] = pkkA[kbi][0]; pa[1] = pkkA[kbi][1];
            pa[2] = pkkA[kbi][2]; pa[3] = pkkA[kbi][3];
            pb[0] = pkkB[kbi][0]; pb[1] = pkkB[kbi][1];
            pb[2] = pkkB[kbi][2]; pb[3] = pkkB[kbi][3];
            int kb = blk * 2 + kbi;
            #pragma unroll
            for (int dj = 0; dj < 2; ++dj) {
                int c = kb * 2 + hh;                 // 0..7
                int slot = c ^ (lane & 7);
                bf16x8 vf = *(const bf16x8*)&Vc[(dj * 32 + L31) * 64 + slot * 8];
                Oa[dj] = __builtin_amdgcn_mfma_f32_32x32x16_bf16(vf, pfA, Oa[dj], 0, 0, 0);
                Ob[dj] = __builtin_amdgcn_mfma_f32_32x32x16_bf16(vf, pfB, Ob[dj], 0, 0, 0);
            }
        }
        __builtin_amdgcn_s_setprio(0);
        __syncthreads();
    }

    // combine hh halves of l within the wave
    lpa += __shfl_xor(lpa, 32);
    lpb += __shfl_xor(lpb, 32);

    // cross-wave (kv-half pair) reduction through the dead K/V LDS.
    float* fb = (float*)smem + qg * 4224;
    if (kvh == 0) {
        #pragma unroll
        for (int dj = 0; dj < 2; ++dj)
            #pragma unroll
            for (int e = 0; e < 16; ++e) {
                fb[(dj * 16 + e) * 64 + lane] = Oa[dj][e];
                fb[(32 + dj * 16 + e) * 64 + lane] = Ob[dj][e];
            }
        fb[4096 + lane] = lpa;
        fb[4160 + lane] = lpb;
    }
    __syncthreads();
    if (kvh == 1) {
        #pragma unroll
        for (int dj = 0; dj < 2; ++dj)
            #pragma unroll
            for (int e = 0; e < 16; ++e) {
                Oa[dj][e] += fb[(dj * 16 + e) * 64 + lane];
                Ob[dj][e] += fb[(32 + dj * 16 + e) * 64 + lane];
            }
        float rla = 1.0f / (lpa + fb[4096 + lane]);
        float rlb = 1.0f / (lpb + fb[4160 + lane]);
        size_t basea = ((size_t)b * SEQ + qrow) * DMODEL + h * HDK;
        #pragma unroll
        for (int dj = 0; dj < 2; ++dj)
            #pragma unroll
            for (int c2 = 0; c2 < 4; ++c2) {
                int d = dj * 32 + 8 * c2 + 4 * hh;
                float4 o;
                o.x = Oa[dj][c2 * 4 + 0] * rla;
                o.y = Oa[dj][c2 * 4 + 1] * rla;
                o.z = Oa[dj][c2 * 4 + 2] * rla;
                o.w = Oa[dj][c2 * 4 + 3] * rla;
                *(float4*)&out[basea + d] = o;
                float4 o2;
                o2.x = Ob[dj][c2 * 4 + 0] * rlb;
                o2.y = Ob[dj][c2 * 4 + 1] * rlb;
                o2.z = Ob[dj][c2 * 4 + 2] * rlb;
                o2.w = Ob[dj][c2 * 4 + 3] * rlb;
                *(float4*)&out[basea + (size_t)32 * DMODEL + d] = o2;
            }
    }
}

// ---------------------------------------------------------------------------
extern "C" void kernel_launch(void* const* d_in, const int* in_sizes, int n_in,
                              void* d_out, int out_size, void* d_ws, size_t ws_size,
                              hipStream_t stream) {
    (void)in_sizes; (void)n_in; (void)out_size;
    const float* query = (const float*)d_in[0];
    const float* key   = (const float*)d_in[1];
    const float* value = (const float*)d_in[2];
    const float* mask  = (const float*)d_in[3];
    const float* Wq    = (const float*)d_in[4];
    const float* bq    = (const float*)d_in[5];
    const float* Wk    = (const float*)d_in[6];
    const float* bk    = (const float*)d_in[7];
    const float* Wv    = (const float*)d_in[8];
    const float* bv    = (const float*)d_in[9];

    const size_t WT_BYTES  = (size_t)3 * DMODEL * DMODEL * 2;       //  3.5 MB
    const size_t ABF_BYTES = (size_t)3 * NB * SEQ * DMODEL * 2;     // 37.7 MB
    const size_t QKV_BYTES = (size_t)NB * NH * SEQ * HDK * 2;       // 12.6 MB

    unsigned short* Wt = (unsigned short*)d_ws;
    if (ws_size >= WT_BYTES + ABF_BYTES + 3 * QKV_BYTES) {
        unsigned short* Abf = (unsigned short*)((char*)d_ws + WT_BYTES);
        unsigned short* Qw = (unsigned short*)((char*)d_ws + WT_BYTES + ABF_BYTES);
        unsigned short* Kw = (unsigned short*)((char*)d_ws + WT_BYTES + ABF_BYTES + QKV_BYTES);
        unsigned short* Vt = (unsigned short*)((char*)d_ws + WT_BYTES + ABF_BYTES + 2 * QKV_BYTES);
        wt_kernel<<<dim3(24, 24, 3), 256, 0, stream>>>(Wq, Wk, Wv, Wt);
        abf_kernel<<<dim3(768, 3), 256, 0, stream>>>(query, key, value, Abf);
        qkv_gemm9<<<dim3(1152), 256, 0, stream>>>(Abf, Wt, bq, bk, bv, Qw, Kw, Vt);
        attn_kernel<<<dim3(768), 256, 0, stream>>>(Qw, Kw, Vt, mask, (float*)d_out);
    } else {
        unsigned short* Qw = (unsigned short*)((char*)d_ws + WT_BYTES);
        unsigned short* Kw = (unsigned short*)((char*)d_ws + WT_BYTES + QKV_BYTES);
        unsigned short* Vt = (unsigned short*)((char*)d_ws + WT_BYTES + 2 * QKV_BYTES);
        wt_kernel<<<dim3(24, 24, 3), 256, 0, stream>>>(Wq, Wk, Wv, Wt);
        qkv_gemm4<<<dim3(1152), 256, 0, stream>>>(query, key, value, Wt,
                                                  bq, bk, bv, Qw, Kw, Vt);
        attn_kernel<<<dim3(768), 256, 0, stream>>>(Qw, Kw, Vt, mask, (float*)d_out);
    }
}

// Round 9
// 294.738 us; speedup vs baseline: 1.3069x; 1.1321x over previous
//
#include <hip/hip_runtime.h>
#include <stdint.h>

#define NH 12
#define DMODEL 768
#define HDK 64
#define SEQ 4096
#define NB 2

typedef __attribute__((ext_vector_type(8))) short bf16x8;
typedef __attribute__((ext_vector_type(4))) short s16x4;
typedef __attribute__((ext_vector_type(4))) float f32x4;
typedef __attribute__((ext_vector_type(16))) float f32x16;

#define LOG2E 1.44269504f
#define QSCALE 0.18033688f   /* 0.125 * log2(e), folded into Q at projection */
#define CSUB 4.0f            /* fixed softmax shift; |score*log2e| < 4 */
/* Round-7 lesson: runtime branch inside the unrolled softmax loop ->
   register-join pressure, 125->232us. Softmax stays straight-line.
   Round-8 lesson: triple-buffer/counted-vmcnt qkv (2 barriers/kt) is 38us
   WORSE than the single-syncthreads 2-phase loop. gemm8 is the keeper. */

__device__ __forceinline__ unsigned short f2bf(float x) {
    union { float f; unsigned u; } v; v.f = x;
    unsigned r = v.u + 0x7FFFu + ((v.u >> 16) & 1u);
    return (unsigned short)(r >> 16);
}

// pack two fp32 -> two bf16, round-half-up (2 add + 1 perm)
__device__ __forceinline__ unsigned pack2bf(float a, float b) {
    union { float f; unsigned u; } x, y; x.f = a; y.f = b;
    return __builtin_amdgcn_perm(y.u + 0x8000u, x.u + 0x8000u, 0x07060302u);
}

// pack two fp32 -> two bf16, TRUNCATING (1 perm); P only (bias cancels in ratio)
__device__ __forceinline__ unsigned pack2bf_t(float a, float b) {
    union { float f; unsigned u; } x, y; x.f = a; y.f = b;
    return __builtin_amdgcn_perm(y.u, x.u, 0x07060302u);
}

// async global -> LDS: dest = wave-uniform base + lane*16
__device__ __forceinline__ void lds_dma16(const void* g, void* l) {
    __builtin_amdgcn_global_load_lds(
        (const __attribute__((address_space(1))) void*)g,
        (__attribute__((address_space(3))) void*)l, 16, 0, 0);
}

// ---------------------------------------------------------------------------
// Kernel 1 (fused prep): blocks [0,2304) = A fp32 -> bf16 one-shot;
// blocks [2304,4032) = W [k][n] fp32 -> Wt [n][k] bf16 transpose.
// Fusing removes one launch + lets the two BW-bound jobs fill the machine
// together.
// ---------------------------------------------------------------------------
__global__ __launch_bounds__(256) void prep_kernel(
    const float* __restrict__ Aq, const float* __restrict__ Ak,
    const float* __restrict__ Av,
    const float* __restrict__ Wq, const float* __restrict__ Wk,
    const float* __restrict__ Wv,
    unsigned short* __restrict__ Abf, unsigned short* __restrict__ Wt) {
    __shared__ float ts[32][33];
    int lin = blockIdx.x;
    if (lin < 2304) {
        // ---- abf part: 768 blocks x 3 mats ----
        int mat = lin / 768, x = lin - mat * 768;
        const float* A = (mat == 0) ? Aq : ((mat == 1) ? Ak : Av);
        unsigned short* o = Abf + (size_t)mat * NB * SEQ * DMODEL;
        int t = x * 256 + threadIdx.x;
        #pragma unroll
        for (int i = 0; i < 4; ++i) {
            size_t e = ((size_t)i * 196608 + t) * 8;   // 6291456 elems/mat
            float4 lo = *(const float4*)&A[e];
            float4 hi = *(const float4*)&A[e + 4];
            uint4 r;
            r.x = pack2bf(lo.x, lo.y); r.y = pack2bf(lo.z, lo.w);
            r.z = pack2bf(hi.x, hi.y); r.w = pack2bf(hi.z, hi.w);
            *(uint4*)&o[e] = r;
        }
    } else {
        // ---- wt part: 24 x 24 x 3 ----
        int r = lin - 2304;
        int mat = r / 576;
        int r2 = r - mat * 576;
        int kx = r2 / 24, ny = r2 - kx * 24;
        const float* W = (mat == 0) ? Wq : ((mat == 1) ? Wk : Wv);
        unsigned short* out = Wt + (size_t)mat * DMODEL * DMODEL;
        int k0 = kx * 32;
        int n0 = ny * 32;
        int t = threadIdx.x;
        int row = t >> 3, c4 = (t & 7) * 4;
        float4 v = *(const float4*)&W[(size_t)(k0 + row) * DMODEL + n0 + c4];
        ts[row][c4 + 0] = v.x; ts[row][c4 + 1] = v.y;
        ts[row][c4 + 2] = v.z; ts[row][c4 + 3] = v.w;
        __syncthreads();
        s16x4 o;
        o[0] = (short)f2bf(ts[c4 + 0][row]);
        o[1] = (short)f2bf(ts[c4 + 1][row]);
        o[2] = (short)f2bf(ts[c4 + 2][row]);
        o[3] = (short)f2bf(ts[c4 + 3][row]);
        *(s16x4*)&out[(size_t)(n0 + row) * DMODEL + k0 + c4] = o;
    }
}

// ---------------------------------------------------------------------------
// Kernel 1-fallback: standalone wt (small-workspace path only).
// ---------------------------------------------------------------------------
__global__ __launch_bounds__(256) void wt_kernel(
    const float* __restrict__ Wq, const float* __restrict__ Wk,
    const float* __restrict__ Wv, unsigned short* __restrict__ Wt) {
    __shared__ float ts[32][33];
    int mat = blockIdx.z;
    const float* W = (mat == 0) ? Wq : ((mat == 1) ? Wk : Wv);
    unsigned short* out = Wt + (size_t)mat * DMODEL * DMODEL;
    int k0 = blockIdx.x * 32;
    int n0 = blockIdx.y * 32;
    int t = threadIdx.x;
    int row = t >> 3, c4 = (t & 7) * 4;
    float4 v = *(const float4*)&W[(size_t)(k0 + row) * DMODEL + n0 + c4];
    ts[row][c4 + 0] = v.x; ts[row][c4 + 1] = v.y;
    ts[row][c4 + 2] = v.z; ts[row][c4 + 3] = v.w;
    __syncthreads();
    s16x4 o;
    o[0] = (short)f2bf(ts[c4 + 0][row]);
    o[1] = (short)f2bf(ts[c4 + 1][row]);
    o[2] = (short)f2bf(ts[c4 + 2][row]);
    o[3] = (short)f2bf(ts[c4 + 3][row]);
    *(s16x4*)&out[(size_t)(n0 + row) * DMODEL + k0 + c4] = o;
}

// ---------------------------------------------------------------------------
// Kernel 2 (primary): QKV GEMM v8 — verbatim round-6 (best measured total).
// Single-barrier 2-phase K-loop + LDS-transposed coalesced epilogue.
// ---------------------------------------------------------------------------
__global__ __launch_bounds__(256, 3) void qkv_gemm8(
    const unsigned short* __restrict__ Abf, const unsigned short* __restrict__ Wt,
    const float* __restrict__ bq, const float* __restrict__ bk,
    const float* __restrict__ bv,
    unsigned short* __restrict__ Qw, unsigned short* __restrict__ Kw,
    unsigned short* __restrict__ Vt) {
    __shared__ __align__(16) char smem[32768];
    unsigned short* AsB = (unsigned short*)smem;            // [2][4096] shorts
    unsigned short* BsB = (unsigned short*)(smem + 16384);  // [2][4096] shorts
    unsigned short* T   = (unsigned short*)smem;            // epilogue [128][128]

    int lin = blockIdx.x;
    int swz = (lin & 7) * 144 + (lin >> 3);   // XCD-chunked (1152 % 8 == 0)
    int mat = swz / 384;
    int rr = swz - mat * 384;
    int mblk = rr / 6;
    int nblk = rr - mblk * 6;                 // n fastest: A-panel sharers adjacent
    const unsigned short* A = Abf + (size_t)mat * NB * SEQ * DMODEL;
    const unsigned short* W = Wt + (size_t)mat * DMODEL * DMODEL;
    const float* bias = (mat == 0) ? bq : ((mat == 1) ? bk : bv);
    int m0 = mblk * 128;
    int n0 = nblk * 128;
    int tid = threadIdx.x;
    int lane = tid & 63, wv = tid >> 6;
    int wm = (wv & 1) * 64, wn = (wv >> 1) * 64;
    int lm = lane & 15, quad = lane >> 4;

    const unsigned short* aS[2];
    const unsigned short* bS[2];
    #pragma unroll
    for (int i = 0; i < 2; ++i) {
        int g = i * 256 + tid;
        int R = g >> 2, c = g & 3, ch = c ^ (R & 3);
        aS[i] = A + (size_t)(m0 + R) * DMODEL + ch * 8;
        bS[i] = W + (size_t)(n0 + R) * DMODEL + ch * 8;
    }

    f32x4 acc[4][4] = {};
    const int sx3 = lm & 3;
    const bool swapC = (mat < 2);

    #pragma unroll
    for (int i = 0; i < 2; ++i) {
        lds_dma16(aS[i], AsB + (i * 256 + wv * 64) * 8);
        lds_dma16(bS[i], BsB + (i * 256 + wv * 64) * 8);
        aS[i] += 32; bS[i] += 32;
    }
    __syncthreads();

    for (int kt = 0; kt < 24; ++kt) {
        int cur = kt & 1;
        if (kt < 23) {
            unsigned short* ad = AsB + (cur ^ 1) * 4096;
            unsigned short* bd = BsB + (cur ^ 1) * 4096;
            #pragma unroll
            for (int i = 0; i < 2; ++i) {
                lds_dma16(aS[i], ad + (i * 256 + wv * 64) * 8);
                lds_dma16(bS[i], bd + (i * 256 + wv * 64) * 8);
                aS[i] += 32; bS[i] += 32;
            }
        }
        const unsigned short* Ac = AsB + cur * 4096;
        const unsigned short* Bc = BsB + cur * 4096;
        bf16x8 af[4], bfr[4];
        #pragma unroll
        for (int i = 0; i < 4; ++i)
            af[i] = *(const bf16x8*)&Ac[(wm + i * 16 + lm) * 32 +
                                        ((quad ^ sx3) << 3)];
        #pragma unroll
        for (int j = 0; j < 4; ++j)
            bfr[j] = *(const bf16x8*)&Bc[(wn + j * 16 + lm) * 32 +
                                         ((quad ^ sx3) << 3)];
        if (swapC) {
            #pragma unroll
            for (int i = 0; i < 4; ++i)
                #pragma unroll
                for (int j = 0; j < 4; ++j)
                    acc[i][j] = __builtin_amdgcn_mfma_f32_16x16x32_bf16(
                        bfr[j], af[i], acc[i][j], 0, 0, 0);
        } else {
            #pragma unroll
            for (int i = 0; i < 4; ++i)
                #pragma unroll
                for (int j = 0; j < 4; ++j)
                    acc[i][j] = __builtin_amdgcn_mfma_f32_16x16x32_bf16(
                        af[i], bfr[j], acc[i][j], 0, 0, 0);
        }
        __syncthreads();   // drains this kt's reads + the prefetch DMAs
    }

    // ---- epilogue phase 1: bias+scale+pack into LDS tile (swizzled) ----
    if (swapC) {
        float sc = (mat == 0) ? QSCALE : 1.0f;
        #pragma unroll
        for (int j = 0; j < 4; ++j) {
            int nb = wn + j * 16 + quad * 4;
            f32x4 bvv = *(const f32x4*)&bias[n0 + nb];
            #pragma unroll
            for (int i = 0; i < 4; ++i) {
                int s = wm + i * 16 + lm;
                s16x4 o;
                #pragma unroll
                for (int r = 0; r < 4; ++r)
                    o[r] = (short)f2bf((acc[i][j][r] + bvv[r]) * sc);
                int idx = s * 128 + ((((nb >> 3) ^ (s & 15)) << 3) | (nb & 7));
                *(s16x4*)&T[idx] = o;
            }
        }
    } else {
        #pragma unroll
        for (int j = 0; j < 4; ++j) {
            int n = wn + j * 16 + lm;
            float bvv = bias[n0 + n];
            #pragma unroll
            for (int i = 0; i < 4; ++i) {
                int mg = wm + i * 16 + quad * 4;
                s16x4 o;
                #pragma unroll
                for (int r = 0; r < 4; ++r) o[r] = (short)f2bf(acc[i][j][r] + bvv);
                int idx = n * 128 + ((((mg >> 3) ^ (n & 15)) << 3) | (mg & 7));
                *(s16x4*)&T[idx] = o;
            }
        }
    }
    __syncthreads();

    // ---- epilogue phase 2: coalesced readout (8 x 16B per thread) ----
    int row8 = tid >> 4, chunk = tid & 15;
    if (swapC) {
        unsigned short* outp = (mat == 0) ? Qw : Kw;
        int n = chunk * 8;
        int h = (n0 + n) >> 6, dk = (n0 + n) & 63;
        #pragma unroll
        for (int it = 0; it < 8; ++it) {
            int rrow = it * 16 + row8;
            int s = m0 + rrow;
            int b = s >> 12, ss = s & 4095;
            uint4 v = *(const uint4*)&T[rrow * 128 +
                                        ((chunk ^ (rrow & 15)) << 3)];
            *(uint4*)&outp[((size_t)(b * NH + h) * SEQ + ss) * HDK + dk] = v;
        }
    } else {
        int s = m0 + chunk * 8;
        int b = s >> 12, ss = s & 4095;
        #pragma unroll
        for (int it = 0; it < 8; ++it) {
            int rrow = it * 16 + row8;
            int dk = (n0 + rrow) & 63, h = (n0 + rrow) >> 6;
            uint4 v = *(const uint4*)&T[rrow * 128 +
                                        ((chunk ^ (rrow & 15)) << 3)];
            *(uint4*)&Vt[((size_t)(b * NH + h) * HDK + dk) * SEQ + ss] = v;
        }
    }
}

// ---------------------------------------------------------------------------
// Kernel 2 (fallback, small workspace): fp32 A staged raw, converted in-loop.
// ---------------------------------------------------------------------------
__global__ __launch_bounds__(256) void qkv_gemm4(
    const float* __restrict__ Aq, const float* __restrict__ Ak,
    const float* __restrict__ Av, const unsigned short* __restrict__ Wt,
    const float* __restrict__ bq, const float* __restrict__ bk,
    const float* __restrict__ bv,
    unsigned short* __restrict__ Qw, unsigned short* __restrict__ Kw,
    unsigned short* __restrict__ Vt) {
    __shared__ float As[128 * 64];
    __shared__ unsigned short Bs[128 * 64];
    int lin = blockIdx.x;
    int swz = (lin & 7) * 144 + (lin >> 3);
    int mat = swz / 384;
    int rr = swz - mat * 384;
    int mblk = rr / 6;
    int nblk = rr - mblk * 6;
    const float* A = (mat == 0) ? Aq : ((mat == 1) ? Ak : Av);
    const unsigned short* W = Wt + (size_t)mat * DMODEL * DMODEL;
    const float* bias = (mat == 0) ? bq : ((mat == 1) ? bk : bv);
    int m0 = mblk * 128;
    int n0 = nblk * 128;
    int tid = threadIdx.x;
    int lane = tid & 63, wv = tid >> 6;
    int wm = (wv & 1) * 64, wn = (wv >> 1) * 64;
    int lm = lane & 15, quad = lane >> 4;

    const float* aS[8];
    float* aD[8];
    #pragma unroll
    for (int i = 0; i < 8; ++i) {
        int g = i * 256 + tid;
        int R = g >> 4, S = g & 15, c = (S & 8) | ((S & 7) ^ (R & 7));
        aS[i] = A + (size_t)(m0 + R) * DMODEL + c * 4;
        aD[i] = &As[(i * 256 + wv * 64) * 4];
    }
    const unsigned short* bS[4];
    unsigned short* bD[4];
    #pragma unroll
    for (int i = 0; i < 4; ++i) {
        int g = i * 256 + tid;
        int R = g >> 3, S = g & 7, c = S ^ (R & 7);
        bS[i] = W + (size_t)(n0 + R) * DMODEL + c * 8;
        bD[i] = &Bs[(i * 256 + wv * 64) * 8];
    }

    f32x4 acc[4][4] = {};
    int sx = lm & 7;
    const bool swapC = (mat < 2);
    for (int kt = 0; kt < 12; ++kt) {
        __syncthreads();
        #pragma unroll
        for (int i = 0; i < 8; ++i) lds_dma16(aS[i], aD[i]);
        #pragma unroll
        for (int i = 0; i < 4; ++i) lds_dma16(bS[i], bD[i]);
        #pragma unroll
        for (int i = 0; i < 8; ++i) aS[i] += 64;
        #pragma unroll
        for (int i = 0; i < 4; ++i) bS[i] += 64;
        __syncthreads();
        #pragma unroll
        for (int ks = 0; ks < 2; ++ks) {
            bf16x8 af[4], bfr[4];
            #pragma unroll
            for (int i = 0; i < 4; ++i) {
                int r = wm + i * 16 + lm;
                int c0 = ks * 8 + quad * 2;
                int s0 = (c0 & 8) | ((c0 & 7) ^ sx);
                int s1 = (c0 & 8) | (((c0 + 1) & 7) ^ sx);
                f32x4 lo = *(const f32x4*)&As[r * 64 + s0 * 4];
                f32x4 hi = *(const f32x4*)&As[r * 64 + s1 * 4];
                unsigned* au = (unsigned*)&af[i];
                au[0] = pack2bf(lo[0], lo[1]);
                au[1] = pack2bf(lo[2], lo[3]);
                au[2] = pack2bf(hi[0], hi[1]);
                au[3] = pack2bf(hi[2], hi[3]);
            }
            #pragma unroll
            for (int j = 0; j < 4; ++j)
                bfr[j] = *(const bf16x8*)&Bs[(wn + j * 16 + lm) * 64 +
                                             (((ks * 4 + quad) ^ sx) << 3)];
            if (swapC) {
                #pragma unroll
                for (int i = 0; i < 4; ++i)
                    #pragma unroll
                    for (int j = 0; j < 4; ++j)
                        acc[i][j] = __builtin_amdgcn_mfma_f32_16x16x32_bf16(
                            bfr[j], af[i], acc[i][j], 0, 0, 0);
            } else {
                #pragma unroll
                for (int i = 0; i < 4; ++i)
                    #pragma unroll
                    for (int j = 0; j < 4; ++j)
                        acc[i][j] = __builtin_amdgcn_mfma_f32_16x16x32_bf16(
                            af[i], bfr[j], acc[i][j], 0, 0, 0);
            }
        }
    }
    if (swapC) {
        float sc = (mat == 0) ? QSCALE : 1.0f;
        unsigned short* outp = (mat == 0) ? Qw : Kw;
        #pragma unroll
        for (int j = 0; j < 4; ++j) {
            int nbase = n0 + wn + j * 16 + quad * 4;
            f32x4 bvv = *(const f32x4*)&bias[nbase];
            int h = nbase >> 6, dk = nbase & 63;
            #pragma unroll
            for (int i = 0; i < 4; ++i) {
                int s = m0 + wm + i * 16 + lm;
                int b = s >> 12, ss = s & 4095;
                s16x4 o;
                #pragma unroll
                for (int r = 0; r < 4; ++r)
                    o[r] = (short)f2bf((acc[i][j][r] + bvv[r]) * sc);
                *(s16x4*)&outp[((size_t)(b * NH + h) * SEQ + ss) * HDK + dk] = o;
            }
        }
    } else {
        #pragma unroll
        for (int j = 0; j < 4; ++j) {
            int n = n0 + wn + j * 16 + lm;
            float bvv = bias[n];
            int h = n >> 6, dk = n & 63;
            #pragma unroll
            for (int i = 0; i < 4; ++i) {
                int mg = m0 + wm + i * 16 + quad * 4;
                int b = mg >> 12, s = mg & 4095;
                s16x4 o;
                #pragma unroll
                for (int r = 0; r < 4; ++r) o[r] = (short)f2bf(acc[i][j][r] + bvv);
                *(s16x4*)&Vt[((size_t)(b * NH + h) * HDK + dk) * SEQ + s] = o;
            }
        }
    }
}

// ---------------------------------------------------------------------------
// Kernel 3: flash attention — FROZEN round-6 kernel verbatim (125.0us,
// MfmaUtil 36.5, VALUBusy 53, no spill). kv-split, KVBLK=64, dbuf K+V,
// one __syncthreads/tile, (256,3), grid 768 = 3 blocks/CU co-resident.
// ---------------------------------------------------------------------------
__global__ __launch_bounds__(256, 3) void attn_kernel(
    const unsigned short* __restrict__ Qw, const unsigned short* __restrict__ Kw,
    const unsigned short* __restrict__ Vt, const float* __restrict__ mask,
    float* __restrict__ out) {
    __shared__ __align__(16) char smem[33792];
    unsigned short* KsB = (unsigned short*)smem;            // [2][4096] shorts
    unsigned short* VsB = (unsigned short*)(smem + 16384);  // [2][4096] shorts
    float* addsB = (float*)(smem + 32768);                  // [2][64]
    // epilogue reuses smem as float fb[2][4224]

    int lin = blockIdx.x;
    int swz = (lin & 7) * 96 + (lin >> 3);      // 768 % 8 == 0 -> bijective
    int q0 = (swz & 31) * 128;
    int bh = swz >> 5;                          // 3 bh per XCD chunk
    int b = bh / NH, h = bh % NH;
    const unsigned short* Qb = Qw + (size_t)bh * SEQ * HDK;
    const char* Kb8 = (const char*)(Kw + (size_t)bh * SEQ * HDK);
    const char* Vb8 = (const char*)(Vt + (size_t)bh * HDK * SEQ);
    const float* mb = mask + (size_t)b * SEQ;
    int tid = threadIdx.x;
    int lane = tid & 63, wv = tid >> 6;         // 4 waves
    int qg = wv >> 1, kvh = wv & 1;
    int L31 = lane & 31, hh = lane >> 5;
    const int sx7 = L31 & 7;

    // Q fragments for both 32-row q-groups of this wave's 64-q span
    int qrow = q0 + qg * 64 + L31;
    bf16x8 qa[4], qbv[4];
    #pragma unroll
    for (int t = 0; t < 4; ++t) {
        qa[t] = *(const bf16x8*)&Qb[(size_t)qrow * HDK + t * 16 + hh * 8];
        qbv[t] = *(const bf16x8*)&Qb[(size_t)(qrow + 32) * HDK + t * 16 + hh * 8];
    }

    // 32-bit per-lane DMA offsets; 2 K-chunks + 2 V-chunks per wave (cc 0..7)
    unsigned koff[2], voff[2];
    #pragma unroll
    for (int i = 0; i < 2; ++i) {
        int cc = wv * 2 + i;
        {
            int rho = cc * 8 + (lane >> 3);     // 0..63
            int blk = rho >> 5, c = (rho >> 3) & 3, hb = (rho >> 2) & 1, r2 = rho & 3;
            int kc = blk * 32 + (c & 1) * 16 + hb * 8 + (c >> 1) * 4 + r2;
            int ch = (lane & 7) ^ (rho & 7);
            koff[i] = (unsigned)((kc * HDK + ch * 8) * 2);
        }
        {
            int d = cc * 8 + (lane >> 3);       // 0..63
            int c = lane & 7;
            int ch = c ^ (d & 7);
            voff[i] = (unsigned)((d * SEQ + ch * 8) * 2);
        }
    }

    // mask: adds[0] for tile 0; mnext carries tile kt+1's mask value (wave 0)
    float mnext = 0.0f;
    if (tid < 64) {
        addsB[tid] = ((1.0f - mb[tid]) * -10000.0f - CSUB) * LOG2E;
        mnext = mb[64 + tid];
    }
    // prologue: stage K(0), V(0)
    #pragma unroll
    for (int i = 0; i < 2; ++i) {
        lds_dma16(Kb8 + koff[i], KsB + (wv * 2 + i) * 512);
        lds_dma16(Vb8 + voff[i], VsB + (wv * 2 + i) * 512);
    }
    __syncthreads();

    f32x16 Oa[2] = {}, Ob[2] = {};
    float lpa = 0.0f, lpb = 0.0f;
    const f32x16 kZero = {};
    const int blk = kvh;                         // this wave's 32-kv half

    for (int kt = 0; kt < 64; ++kt) {
        int cur = kt & 1;
        const unsigned short* Kc = KsB + cur * 4096;
        const unsigned short* Vc = VsB + cur * 4096;
        const float* adc = addsB + cur * 64;
        // prefetch kt+1 (covered by this tile's compute; drained by the sync)
        if (kt < 63) {
            const char* Kt8 = Kb8 + (size_t)(kt + 1) * 8192;
            const char* Vt8 = Vb8 + (size_t)(kt + 1) * 128;
            unsigned short* kd = KsB + (cur ^ 1) * 4096;
            unsigned short* vd = VsB + (cur ^ 1) * 4096;
            #pragma unroll
            for (int i = 0; i < 2; ++i) {
                lds_dma16(Kt8 + koff[i], kd + (wv * 2 + i) * 512);
                lds_dma16(Vt8 + voff[i], vd + (wv * 2 + i) * 512);
            }
        }
        if (tid < 64) {
            addsB[(cur ^ 1) * 64 + tid] =
                ((1.0f - mnext) * -10000.0f - CSUB) * LOG2E;
            int mi = (kt < 62) ? (kt + 2) * 64 + tid : tid;
            mnext = mb[mi];
        }

        // S^T 32x32: A = K_perm rows [32blk..), B = Q; kf feeds both q-groups
        f32x16 sa, sb;
        __builtin_amdgcn_s_setprio(1);
        {
            bf16x8 kf = *(const bf16x8*)&Kc[(blk * 32 + L31) * 64 +
                                            ((hh ^ sx7) << 3)];
            sa = __builtin_amdgcn_mfma_f32_32x32x16_bf16(kf, qa[0], kZero, 0, 0, 0);
            sb = __builtin_amdgcn_mfma_f32_32x32x16_bf16(kf, qbv[0], kZero, 0, 0, 0);
        }
        #pragma unroll
        for (int t = 1; t < 4; ++t) {
            bf16x8 kf = *(const bf16x8*)&Kc[(blk * 32 + L31) * 64 +
                                            (((2 * t + hh) ^ sx7) << 3)];
            sa = __builtin_amdgcn_mfma_f32_32x32x16_bf16(kf, qa[t], sa, 0, 0, 0);
            sb = __builtin_amdgcn_mfma_f32_32x32x16_bf16(kf, qbv[t], sb, 0, 0, 0);
        }
        __builtin_amdgcn_s_setprio(0);

        // softmax; l accumulated in f32
        unsigned pkkA[2][4], pkkB[2][4];
        #pragma unroll
        for (int c2 = 0; c2 < 4; ++c2) {
            f32x4 adv = *(const f32x4*)&adc[blk * 32 + (c2 & 1) * 16 +
                                            (c2 >> 1) * 4 + hh * 8];
            float a0 = __builtin_amdgcn_exp2f(sa[c2 * 4 + 0] + adv[0]);
            float a1 = __builtin_amdgcn_exp2f(sa[c2 * 4 + 1] + adv[1]);
            float a2 = __builtin_amdgcn_exp2f(sa[c2 * 4 + 2] + adv[2]);
            float a3 = __builtin_amdgcn_exp2f(sa[c2 * 4 + 3] + adv[3]);
            lpa += (a0 + a1) + (a2 + a3);
            pkkA[c2 & 1][2 * (c2 >> 1) + 0] = pack2bf_t(a0, a1);
            pkkA[c2 & 1][2 * (c2 >> 1) + 1] = pack2bf_t(a2, a3);
            float b0v = __builtin_amdgcn_exp2f(sb[c2 * 4 + 0] + adv[0]);
            float b1v = __builtin_amdgcn_exp2f(sb[c2 * 4 + 1] + adv[1]);
            float b2v = __builtin_amdgcn_exp2f(sb[c2 * 4 + 2] + adv[2]);
            float b3v = __builtin_amdgcn_exp2f(sb[c2 * 4 + 3] + adv[3]);
            lpb += (b0v + b1v) + (b2v + b3v);
            pkkB[c2 & 1][2 * (c2 >> 1) + 0] = pack2bf_t(b0v, b1v);
            pkkB[c2 & 1][2 * (c2 >> 1) + 1] = pack2bf_t(b2v, b3v);
        }

        // O^T += V^T . P^T for this wave's kv-half
        __builtin_amdgcn_s_setprio(1);
        #pragma unroll
        for (int kbi = 0; kbi < 2; ++kbi) {
            bf16x8 pfA, pfB;
            unsigned* pa = (unsigned*)&pfA;
            unsigned* pb = (unsigned*)&pfB;
            pa[0] = pkkA[kbi][0]; pa[1] = pkkA[kbi][1];
            pa[2] = pkkA[kbi][2]; pa[3] = pkkA[kbi][3];
            pb[0] = pkkB[kbi][0]; pb[1] = pkkB[kbi][1];
            pb[2] = pkkB[kbi][2]; pb[3] = pkkB[kbi][3];
            int kb = blk * 2 + kbi;
            #pragma unroll
            for (int dj = 0; dj < 2; ++dj) {
                int c = kb * 2 + hh;                 // 0..7
                int slot = c ^ (lane & 7);
                bf16x8 vf = *(const bf16x8*)&Vc[(dj * 32 + L31) * 64 + slot * 8];
                Oa[dj] = __builtin_amdgcn_mfma_f32_32x32x16_bf16(vf, pfA, Oa[dj], 0, 0, 0);
                Ob[dj] = __builtin_amdgcn_mfma_f32_32x32x16_bf16(vf, pfB, Ob[dj], 0, 0, 0);
            }
        }
        __builtin_amdgcn_s_setprio(0);
        __syncthreads();
    }

    // combine hh halves of l within the wave
    lpa += __shfl_xor(lpa, 32);
    lpb += __shfl_xor(lpb, 32);

    // cross-wave (kv-half pair) reduction through the dead K/V LDS.
    float* fb = (float*)smem + qg * 4224;
    if (kvh == 0) {
        #pragma unroll
        for (int dj = 0; dj < 2; ++dj)
            #pragma unroll
            for (int e = 0; e < 16; ++e) {
                fb[(dj * 16 + e) * 64 + lane] = Oa[dj][e];
                fb[(32 + dj * 16 + e) * 64 + lane] = Ob[dj][e];
            }
        fb[4096 + lane] = lpa;
        fb[4160 + lane] = lpb;
    }
    __syncthreads();
    if (kvh == 1) {
        #pragma unroll
        for (int dj = 0; dj < 2; ++dj)
            #pragma unroll
            for (int e = 0; e < 16; ++e) {
                Oa[dj][e] += fb[(dj * 16 + e) * 64 + lane];
                Ob[dj][e] += fb[(32 + dj * 16 + e) * 64 + lane];
            }
        float rla = 1.0f / (lpa + fb[4096 + lane]);
        float rlb = 1.0f / (lpb + fb[4160 + lane]);
        size_t basea = ((size_t)b * SEQ + qrow) * DMODEL + h * HDK;
        #pragma unroll
        for (int dj = 0; dj < 2; ++dj)
            #pragma unroll
            for (int c2 = 0; c2 < 4; ++c2) {
                int d = dj * 32 + 8 * c2 + 4 * hh;
                float4 o;
                o.x = Oa[dj][c2 * 4 + 0] * rla;
                o.y = Oa[dj][c2 * 4 + 1] * rla;
                o.z = Oa[dj][c2 * 4 + 2] * rla;
                o.w = Oa[dj][c2 * 4 + 3] * rla;
                *(float4*)&out[basea + d] = o;
                float4 o2;
                o2.x = Ob[dj][c2 * 4 + 0] * rlb;
                o2.y = Ob[dj][c2 * 4 + 1] * rlb;
                o2.z = Ob[dj][c2 * 4 + 2] * rlb;
                o2.w = Ob[dj][c2 * 4 + 3] * rlb;
                *(float4*)&out[basea + (size_t)32 * DMODEL + d] = o2;
            }
    }
}

// ---------------------------------------------------------------------------
extern "C" void kernel_launch(void* const* d_in, const int* in_sizes, int n_in,
                              void* d_out, int out_size, void* d_ws, size_t ws_size,
                              hipStream_t stream) {
    (void)in_sizes; (void)n_in; (void)out_size;
    const float* query = (const float*)d_in[0];
    const float* key   = (const float*)d_in[1];
    const float* value = (const float*)d_in[2];
    const float* mask  = (const float*)d_in[3];
    const float* Wq    = (const float*)d_in[4];
    const float* bq    = (const float*)d_in[5];
    const float* Wk    = (const float*)d_in[6];
    const float* bk    = (const float*)d_in[7];
    const float* Wv    = (const float*)d_in[8];
    const float* bv    = (const float*)d_in[9];

    const size_t WT_BYTES  = (size_t)3 * DMODEL * DMODEL * 2;       //  3.5 MB
    const size_t ABF_BYTES = (size_t)3 * NB * SEQ * DMODEL * 2;     // 37.7 MB
    const size_t QKV_BYTES = (size_t)NB * NH * SEQ * HDK * 2;       // 12.6 MB

    unsigned short* Wt = (unsigned short*)d_ws;
    if (ws_size >= WT_BYTES + ABF_BYTES + 3 * QKV_BYTES) {
        unsigned short* Abf = (unsigned short*)((char*)d_ws + WT_BYTES);
        unsigned short* Qw = (unsigned short*)((char*)d_ws + WT_BYTES + ABF_BYTES);
        unsigned short* Kw = (unsigned short*)((char*)d_ws + WT_BYTES + ABF_BYTES + QKV_BYTES);
        unsigned short* Vt = (unsigned short*)((char*)d_ws + WT_BYTES + ABF_BYTES + 2 * QKV_BYTES);
        prep_kernel<<<dim3(4032), 256, 0, stream>>>(query, key, value,
                                                    Wq, Wk, Wv, Abf, Wt);
        qkv_gemm8<<<dim3(1152), 256, 0, stream>>>(Abf, Wt, bq, bk, bv, Qw, Kw, Vt);
        attn_kernel<<<dim3(768), 256, 0, stream>>>(Qw, Kw, Vt, mask, (float*)d_out);
    } else {
        unsigned short* Qw = (unsigned short*)((char*)d_ws + WT_BYTES);
        unsigned short* Kw = (unsigned short*)((char*)d_ws + WT_BYTES + QKV_BYTES);
        unsigned short* Vt = (unsigned short*)((char*)d_ws + WT_BYTES + 2 * QKV_BYTES);
        wt_kernel<<<dim3(24, 24, 3), 256, 0, stream>>>(Wq, Wk, Wv, Wt);
        qkv_gemm4<<<dim3(1152), 256, 0, stream>>>(query, key, value, Wt,
                                                  bq, bk, bv, Qw, Kw, Vt);
        attn_kernel<<<dim3(768), 256, 0, stream>>>(Qw, Kw, Vt, mask, (float*)d_out);
    }
}